// Round 10
// baseline (269.371 us; speedup 1.0000x reference)
//
#include <hip/hip_runtime.h>
#include <cstdint>
#include <cstddef>

#define NN   50000
#define EEN  800000
#define INF_ 256
#define HH   3
#define FEAT 192   // H*D
#define EFD  64
#define NEG_ 0.2f
#define EPSF 1e-12f
#define SMASK 0x0FFFFFF0   // s*16 field in srcP
#define NB   ((NN + 1023) / 1024)

typedef __attribute__((ext_vector_type(8))) short short8;
typedef __attribute__((ext_vector_type(4))) float f32x4;
typedef __attribute__((ext_vector_type(2))) float f32x2;

static __device__ __forceinline__ float4 ld4(const float* p) {
    return *reinterpret_cast<const float4*>(p);
}
static __device__ __forceinline__ uint f2b(float f) {
    union { float f; uint32_t u; } v; v.f = f;
    uint32_t u = v.u;
    return (u + 0x7FFFu + ((u >> 16) & 1u)) >> 16;
}
static __device__ __forceinline__ uint pack2(float a, float b) {
    return f2b(a) | (f2b(b) << 16);
}
static __device__ __forceinline__ float blo(uint u) {
    return __uint_as_float(u << 16);
}
static __device__ __forceinline__ float bhi(uint u) {
    return __uint_as_float(u & 0xFFFF0000u);
}

// ---------------- prep: weight transposes (blocks 0..119) + eetab (120,121) --
static __device__ __forceinline__ void trans_tile(const float* __restrict__ W,
        ushort* __restrict__ BT, int K, int N, int kt, int nt)
{
    __shared__ float tile[32][33];
    const int tx = threadIdx.x & 31, ty = threadIdx.x >> 5;  // 32 x 8
    #pragma unroll
    for (int r = 0; r < 4; ++r) {
        int row = kt * 32 + ty + r * 8;
        int col = nt * 32 + tx;
        tile[ty + r * 8][tx] = W[(size_t)row * N + col];
    }
    __syncthreads();
    #pragma unroll
    for (int r = 0; r < 4; ++r) {
        int n = nt * 32 + ty + r * 8;
        int k = kt * 32 + tx;
        BT[(size_t)n * K + k] = (ushort)f2b(tile[tx][ty + r * 8]);
    }
}

static __device__ __forceinline__ void eetab_calc(const float* __restrict__ Eemb,
        const float* __restrict__ We, const float* __restrict__ ae,
        float* __restrict__ eetab)
{
    __shared__ float t1[3 * 64];
    const int t = threadIdx.x;
    if (t < 192) {
        const int g = t & 63, h = t >> 6;
        const float* wrow = We + g * FEAT + h * EFD;
        const float* av   = ae + h * EFD;
        float s = 0.f;
        #pragma unroll 8
        for (int f = 0; f < EFD; ++f) s += wrow[f] * av[f];
        t1[h * 64 + g] = s;
    }
    __syncthreads();
    if (t < 24) {
        int tt = t / 3, hh = t - tt * 3;
        float acc = 0.f;
        const float* em = Eemb + tt * EFD;
        const float* tv = t1 + hh * 64;
        #pragma unroll 8
        for (int g2 = 0; g2 < 64; ++g2) acc += em[g2] * tv[g2];
        eetab[tt * 3 + hh] = acc;
    }
}

__global__ __launch_bounds__(256) void k_prep(const float* __restrict__ W1,
        ushort* __restrict__ o1, const float* __restrict__ W2,
        ushort* __restrict__ o2, const float* __restrict__ W3,
        ushort* __restrict__ o3,
        const float* __restrict__ Eemb1, const float* __restrict__ We1,
        const float* __restrict__ ae1, float* __restrict__ ee1,
        const float* __restrict__ Eemb2, const float* __restrict__ We2,
        const float* __restrict__ ae2, float* __restrict__ ee2)
{
    int b = blockIdx.x;
    if (b < 48) {            // W1: K=256 (8 ktiles) x N=192 (6 ntiles)
        trans_tile(W1, o1, INF_, FEAT, b & 7, b >> 3);
    } else if (b < 84) {     // W2: 6 x 6
        int i = b - 48;
        trans_tile(W2, o2, FEAT, FEAT, i % 6, i / 6);
    } else if (b < 120) {    // W3: 6 x 6
        int i = b - 84;
        trans_tile(W3, o3, FEAT, FEAT, i % 6, i / 6);
    } else if (b == 120) {
        eetab_calc(Eemb1, We1, ae1, ee1);
    } else {
        eetab_calc(Eemb2, We2, ae2, ee2);
    }
}

// ---------------- GEMM1: 128-row tile, full-N(192), fused el/er --------------
#define LDA 40   // padded LDS row stride (ushort)
__global__ __launch_bounds__(256) void gemm_mfma1(const float* __restrict__ A,
        const ushort* __restrict__ BT, ushort* __restrict__ Cb,
        float4* __restrict__ el4, float4* __restrict__ er4,
        const float* __restrict__ al, const float* __restrict__ ar,
        int M, int K)
{
    __shared__ ushort As[128 * LDA];
    __shared__ ushort Bs[192 * LDA];
    const int t = threadIdx.x;
    const int lane = t & 63, w = t >> 6;
    const int bm = blockIdx.x * 128;
    const int fr = lane & 15;
    const int fq = lane >> 4;
    const int fg = fq * 8;
    const int arow = t >> 1;           // 0..127
    const int acol = (t & 1) * 8;      // 0 or 8 (plus +16 later)
    const int brow = t >> 2;           // 0..63
    const int bcol = (t & 3) * 8;

    f32x4 acc[2][12];
    #pragma unroll
    for (int i = 0; i < 2; ++i)
        #pragma unroll
        for (int c = 0; c < 12; ++c)
            acc[i][c] = (f32x4){0.f, 0.f, 0.f, 0.f};

    const int ga = bm + arow;
    for (int k0 = 0; k0 < K; k0 += 32) {
        uint4 u0 = make_uint4(0,0,0,0), u1 = u0;
        if (ga < M) {
            const float* ap = A + (size_t)ga * K + k0 + acol;
            float4 f0 = ld4(ap), f1 = ld4(ap + 4);
            float4 f2v = ld4(ap + 16), f3 = ld4(ap + 20);
            u0 = make_uint4(pack2(f0.x,f0.y), pack2(f0.z,f0.w),
                            pack2(f1.x,f1.y), pack2(f1.z,f1.w));
            u1 = make_uint4(pack2(f2v.x,f2v.y), pack2(f2v.z,f2v.w),
                            pack2(f3.x,f3.y), pack2(f3.z,f3.w));
        }
        *reinterpret_cast<uint4*>(As + arow * LDA + acol) = u0;
        *reinterpret_cast<uint4*>(As + arow * LDA + acol + 16) = u1;
        #pragma unroll
        for (int j = 0; j < 3; ++j) {
            uint4 bv = *reinterpret_cast<const uint4*>(BT + (size_t)(j * 64 + brow) * K + k0 + bcol);
            *reinterpret_cast<uint4*>(Bs + (j * 64 + brow) * LDA + bcol) = bv;
        }
        __syncthreads();
        short8 afr0 = *reinterpret_cast<const short8*>(As + (w * 32 + fr) * LDA + fg);
        short8 afr1 = *reinterpret_cast<const short8*>(As + (w * 32 + 16 + fr) * LDA + fg);
        #pragma unroll
        for (int c = 0; c < 12; ++c) {
            short8 bfr = *reinterpret_cast<const short8*>(Bs + (c * 16 + fr) * LDA + fg);
            acc[0][c] = __builtin_amdgcn_mfma_f32_16x16x32_bf16(afr0, bfr, acc[0][c], 0, 0, 0);
            acc[1][c] = __builtin_amdgcn_mfma_f32_16x16x32_bf16(afr1, bfr, acc[1][c], 0, 0, 0);
        }
        __syncthreads();
    }
    #pragma unroll
    for (int i = 0; i < 2; ++i) {
        #pragma unroll
        for (int j = 0; j < 4; ++j) {
            int row = bm + w * 32 + i * 16 + fq * 4 + j;
            if (row < M) {
                #pragma unroll
                for (int c = 0; c < 12; ++c)
                    Cb[(size_t)row * FEAT + c * 16 + fr] = (ushort)f2b(acc[i][c][j]);
            }
        }
    }
    float alv[12], arv[12];
    #pragma unroll
    for (int c = 0; c < 12; ++c) {
        alv[c] = al[c * 16 + fr];
        arv[c] = ar[c * 16 + fr];
    }
    #pragma unroll
    for (int i = 0; i < 2; ++i) {
        #pragma unroll
        for (int j = 0; j < 4; ++j) {
            int row = bm + w * 32 + i * 16 + fq * 4 + j;
            float pl0 = 0.f, pl1 = 0.f, pl2 = 0.f;
            float pr0 = 0.f, pr1 = 0.f, pr2 = 0.f;
            #pragma unroll
            for (int c = 0; c < 4; ++c)  { pl0 += acc[i][c][j]*alv[c];  pr0 += acc[i][c][j]*arv[c]; }
            #pragma unroll
            for (int c = 4; c < 8; ++c)  { pl1 += acc[i][c][j]*alv[c];  pr1 += acc[i][c][j]*arv[c]; }
            #pragma unroll
            for (int c = 8; c < 12; ++c) { pl2 += acc[i][c][j]*alv[c];  pr2 += acc[i][c][j]*arv[c]; }
            #pragma unroll
            for (int o = 1; o < 16; o <<= 1) {
                pl0 += __shfl_xor(pl0, o); pl1 += __shfl_xor(pl1, o); pl2 += __shfl_xor(pl2, o);
                pr0 += __shfl_xor(pr0, o); pr1 += __shfl_xor(pr1, o); pr2 += __shfl_xor(pr2, o);
            }
            if (fr == 0 && row < M) {
                el4[row] = make_float4(pl0, pl1, pl2, 0.f);
                er4[row] = make_float4(pr0, pr1, pr2, 0.f);
            }
        }
    }
}

// ---------------- GEMM2: 64-row tile, dual-B, fused el/er --------------------
__global__ __launch_bounds__(256) void gemm_mfma2(const ushort* __restrict__ A,
        const ushort* __restrict__ BT, const ushort* __restrict__ BT2,
        ushort* __restrict__ Cb, ushort* __restrict__ resb,
        float4* __restrict__ el4, float4* __restrict__ er4,
        const float* __restrict__ al, const float* __restrict__ ar,
        int M, int K)
{
    __shared__ ushort As[64 * LDA];
    __shared__ ushort Bs[192 * LDA];
    __shared__ ushort Bs2[192 * LDA];
    const int t = threadIdx.x;
    const int lane = t & 63, w = t >> 6;
    const int bm = blockIdx.x * 64;
    const int fr = lane & 15;
    const int fq = lane >> 4;
    const int fg = fq * 8;
    const int arow = t >> 2;           // 0..63
    const int acol = (t & 3) * 8;
    const int brow = t >> 2;
    const int bcol = (t & 3) * 8;

    f32x4 acc[12], acc2[12];
    #pragma unroll
    for (int c = 0; c < 12; ++c) {
        acc[c] = (f32x4){0.f, 0.f, 0.f, 0.f};
        acc2[c] = (f32x4){0.f, 0.f, 0.f, 0.f};
    }

    const int ga = bm + arow;
    for (int k0 = 0; k0 < K; k0 += 32) {
        uint4 u0 = make_uint4(0,0,0,0);
        if (ga < M)
            u0 = *reinterpret_cast<const uint4*>(A + (size_t)ga * K + k0 + acol);
        *reinterpret_cast<uint4*>(As + arow * LDA + acol) = u0;
        #pragma unroll
        for (int j = 0; j < 3; ++j) {
            uint4 bv = *reinterpret_cast<const uint4*>(BT + (size_t)(j * 64 + brow) * K + k0 + bcol);
            *reinterpret_cast<uint4*>(Bs + (j * 64 + brow) * LDA + bcol) = bv;
            uint4 b2 = *reinterpret_cast<const uint4*>(BT2 + (size_t)(j * 64 + brow) * K + k0 + bcol);
            *reinterpret_cast<uint4*>(Bs2 + (j * 64 + brow) * LDA + bcol) = b2;
        }
        __syncthreads();
        short8 afr = *reinterpret_cast<const short8*>(As + (w * 16 + fr) * LDA + fg);
        #pragma unroll
        for (int c = 0; c < 12; ++c) {
            short8 bfr = *reinterpret_cast<const short8*>(Bs + (c * 16 + fr) * LDA + fg);
            acc[c] = __builtin_amdgcn_mfma_f32_16x16x32_bf16(afr, bfr, acc[c], 0, 0, 0);
            short8 b2 = *reinterpret_cast<const short8*>(Bs2 + (c * 16 + fr) * LDA + fg);
            acc2[c] = __builtin_amdgcn_mfma_f32_16x16x32_bf16(afr, b2, acc2[c], 0, 0, 0);
        }
        __syncthreads();
    }
    #pragma unroll
    for (int j = 0; j < 4; ++j) {
        int row = bm + w * 16 + fq * 4 + j;
        if (row < M) {
            #pragma unroll
            for (int c = 0; c < 12; ++c) {
                Cb[(size_t)row * FEAT + c * 16 + fr] = (ushort)f2b(acc[c][j]);
                resb[(size_t)row * FEAT + c * 16 + fr] = (ushort)f2b(acc2[c][j]);
            }
        }
    }
    float alv[12], arv[12];
    #pragma unroll
    for (int c = 0; c < 12; ++c) {
        alv[c] = al[c * 16 + fr];
        arv[c] = ar[c * 16 + fr];
    }
    #pragma unroll
    for (int j = 0; j < 4; ++j) {
        int row = bm + w * 16 + fq * 4 + j;
        float pl0 = 0.f, pl1 = 0.f, pl2 = 0.f;
        float pr0 = 0.f, pr1 = 0.f, pr2 = 0.f;
        #pragma unroll
        for (int c = 0; c < 4; ++c)  { pl0 += acc[c][j]*alv[c];  pr0 += acc[c][j]*arv[c]; }
        #pragma unroll
        for (int c = 4; c < 8; ++c)  { pl1 += acc[c][j]*alv[c];  pr1 += acc[c][j]*arv[c]; }
        #pragma unroll
        for (int c = 8; c < 12; ++c) { pl2 += acc[c][j]*alv[c];  pr2 += acc[c][j]*arv[c]; }
        #pragma unroll
        for (int o = 1; o < 16; o <<= 1) {
            pl0 += __shfl_xor(pl0, o); pl1 += __shfl_xor(pl1, o); pl2 += __shfl_xor(pl2, o);
            pr0 += __shfl_xor(pr0, o); pr1 += __shfl_xor(pr1, o); pr2 += __shfl_xor(pr2, o);
        }
        if (fr == 0 && row < M) {
            el4[row] = make_float4(pl0, pl1, pl2, 0.f);
            er4[row] = make_float4(pr0, pr1, pr2, 0.f);
        }
    }
}

// ---------------- CSR build --------------------------------------------------
__global__ void k_hist(const int* __restrict__ dst, int* __restrict__ deg) {
    int e = blockIdx.x * blockDim.x + threadIdx.x;
    if (e < EEN) atomicAdd(&deg[dst[e]], 1);
}

__global__ __launch_bounds__(1024) void k_scan1(const int* __restrict__ deg,
        int* __restrict__ off, int* __restrict__ bsum)
{
    __shared__ int wsums[16];
    __shared__ int wexc[16];
    const int tid = threadIdx.x;
    const int lane = tid & 63, wid = tid >> 6;
    int i = blockIdx.x * 1024 + tid;
    int v = (i < NN) ? deg[i] : 0;
    int incl = v;
    #pragma unroll
    for (int o = 1; o < 64; o <<= 1) {
        int u = __shfl_up(incl, o);
        if (lane >= o) incl += u;
    }
    if (lane == 63) wsums[wid] = incl;
    __syncthreads();
    if (wid == 0) {
        int s = (lane < 16) ? wsums[lane] : 0;
        int si = s;
        #pragma unroll
        for (int o = 1; o < 16; o <<= 1) {
            int u = __shfl_up(si, o);
            if (lane >= o) si += u;
        }
        if (lane < 16) wexc[lane] = si - s;
        if (lane == 15) bsum[blockIdx.x] = si;
    }
    __syncthreads();
    if (i < NN) off[i] = wexc[wid] + incl - v;
}

__global__ __launch_bounds__(64) void k_scan2(const int* __restrict__ bsum,
        int* __restrict__ bexc, int* __restrict__ off)
{
    int lane = threadIdx.x;
    int v = (lane < NB) ? bsum[lane] : 0;
    int incl = v;
    #pragma unroll
    for (int o = 1; o < 64; o <<= 1) {
        int u = __shfl_up(incl, o);
        if (lane >= o) incl += u;
    }
    if (lane < NB) bexc[lane] = incl - v;
    if (lane == 63) off[NN] = incl;
}

__global__ __launch_bounds__(1024) void k_scan3(int* __restrict__ off,
        int* __restrict__ cur, const int* __restrict__ bexc)
{
    int i = blockIdx.x * 1024 + threadIdx.x;
    if (i < NN) {
        int o = off[i] + bexc[blockIdx.x];
        off[i] = o;
        cur[i] = o;
    }
}

__global__ void k_scatter(const int* __restrict__ src, const int* __restrict__ dst,
        const int* __restrict__ et, int* __restrict__ cur, int* __restrict__ srcP)
{
    int e = blockIdx.x * blockDim.x + threadIdx.x;
    if (e < EEN) {
        int p = atomicAdd(&cur[dst[e]], 1);
        srcP[p] = (src[e] << 4) | (et[e] << 28);
    }
}

// ---------------- fused edge-softmax + aggregation (wave per node) -----------
// round-7 structure; accumulators as f32x2 -> v_pk_fma_f32 in the gather loop
#define EXTRACT(U, V01, V23) \
    f32x2 V01 = {blo((U).x), bhi((U).x)}; \
    f32x2 V23 = {blo((U).y), bhi((U).y)};

template<bool RES, bool FINAL>
__global__ __launch_bounds__(256) void k_attn_agg(const int* __restrict__ off,
        const int* __restrict__ srcP, const float4* __restrict__ el4,
        const float4* __restrict__ er4, const float* __restrict__ eetab,
        const ushort* __restrict__ featb, const ushort* __restrict__ resb,
        void* __restrict__ outv)
{
    __shared__ float shw[4][64 * 6];
    __shared__ float eet[24];
    const int wid = threadIdx.x >> 6, lane = threadIdx.x & 63;
    if (threadIdx.x < 24) eet[threadIdx.x] = eetab[threadIdx.x];
    __syncthreads();
    const int n = blockIdx.x * 4 + wid;
    if (n >= NN) return;
    const int hd = lane >> 4;                  // 0..2 gather head; 3 = idle
    const char* elc = (const char*)el4;
    const char* fb  = (const char*)featb + lane * 8;
    float* sw = shw[wid];

    const int beg = off[n], end = off[n + 1];
    const float4 erv = er4[n];
    f32x2 acc01 = {0.f, 0.f}, acc23 = {0.f, 0.f};
    float dl0 = 0.f, dl1 = 0.f, dl2 = 0.f;

    for (int c0 = beg; c0 < end; c0 += 64) {
        const int e = c0 + lane;
        float p0 = 0.f, p1 = 0.f, p2 = 0.f;
        int boff = 0;
        if (e < end) {
            int sp = srcP[e];
            int s16 = sp & SMASK;
            int tt = ((unsigned)sp) >> 28;
            float4 ev = *reinterpret_cast<const float4*>(elc + s16);
            float l0 = ev.x + erv.x + eet[tt*3+0];
            float l1 = ev.y + erv.y + eet[tt*3+1];
            float l2 = ev.z + erv.z + eet[tt*3+2];
            l0 = l0 > 0.f ? l0 : NEG_ * l0;
            l1 = l1 > 0.f ? l1 : NEG_ * l1;
            l2 = l2 > 0.f ? l2 : NEG_ * l2;
            p0 = __expf(l0); p1 = __expf(l1); p2 = __expf(l2);
            boff = s16 * 24;                   // s*384 bytes into featb
        }
        dl0 += p0; dl1 += p1; dl2 += p2;
        const float bf = __int_as_float(boff);
        float* sl = sw + lane * 6;
        *reinterpret_cast<float2*>(sl + 0) = make_float2(p0, bf);
        *reinterpret_cast<float2*>(sl + 2) = make_float2(p1, bf);
        *reinterpret_cast<float2*>(sl + 4) = make_float2(p2, bf);
        const int cnt = min(64, end - c0);
        const float* swh = sw + hd * 2;
        int j = 0;
        for (; j + 4 <= cnt; j += 4) {
            if (lane < 48) {
                float2 g0 = *reinterpret_cast<const float2*>(swh + (j+0)*6);
                float2 g1 = *reinterpret_cast<const float2*>(swh + (j+1)*6);
                float2 g2 = *reinterpret_cast<const float2*>(swh + (j+2)*6);
                float2 g3 = *reinterpret_cast<const float2*>(swh + (j+3)*6);
                uint2 u0 = *reinterpret_cast<const uint2*>(fb + __float_as_int(g0.y));
                uint2 u1 = *reinterpret_cast<const uint2*>(fb + __float_as_int(g1.y));
                uint2 u2 = *reinterpret_cast<const uint2*>(fb + __float_as_int(g2.y));
                uint2 u3 = *reinterpret_cast<const uint2*>(fb + __float_as_int(g3.y));
                EXTRACT(u0, a01, a23)
                EXTRACT(u1, b01, b23)
                EXTRACT(u2, c01, c23)
                EXTRACT(u3, d01, d23)
                acc01 += g0.x * a01; acc23 += g0.x * a23;
                acc01 += g1.x * b01; acc23 += g1.x * b23;
                acc01 += g2.x * c01; acc23 += g2.x * c23;
                acc01 += g3.x * d01; acc23 += g3.x * d23;
            }
        }
        for (; j < cnt; ++j) {
            if (lane < 48) {
                float2 gv = *reinterpret_cast<const float2*>(swh + j*6);
                uint2 uu = *reinterpret_cast<const uint2*>(fb + __float_as_int(gv.y));
                EXTRACT(uu, v01, v23)
                acc01 += gv.x * v01; acc23 += gv.x * v23;
            }
        }
    }
    #pragma unroll
    for (int o = 32; o > 0; o >>= 1) {
        dl0 += __shfl_xor(dl0, o);
        dl1 += __shfl_xor(dl1, o);
        dl2 += __shfl_xor(dl2, o);
    }
    const float den = hd == 0 ? dl0 : (hd == 1 ? dl1 : dl2);
    const float inv = 1.f / fmaxf(den, EPSF);
    float acc0 = acc01.x * inv, acc1 = acc01.y * inv;
    float acc2 = acc23.x * inv, acc3 = acc23.y * inv;
    if (RES) {
        if (lane < 48) {
            uint2 r = *reinterpret_cast<const uint2*>((const char*)resb + (size_t)n * 384 + lane * 8);
            acc0 += blo(r.x); acc1 += bhi(r.x);
            acc2 += blo(r.y); acc3 += bhi(r.y);
        }
    }
    acc0 = acc0 > 0.f ? acc0 : expm1f(acc0);
    acc1 = acc1 > 0.f ? acc1 : expm1f(acc1);
    acc2 = acc2 > 0.f ? acc2 : expm1f(acc2);
    acc3 = acc3 > 0.f ? acc3 : expm1f(acc3);
    if (!FINAL) {
        if (lane < 48) {
            ushort4 o4;
            o4.x = (ushort)f2b(acc0); o4.y = (ushort)f2b(acc1);
            o4.z = (ushort)f2b(acc2); o4.w = (ushort)f2b(acc3);
            ((ushort4*)outv)[(size_t)n * 48 + lane] = o4;
        }
    } else {
        float b0 = __shfl(acc0, lane + 16), c0v = __shfl(acc0, lane + 32);
        float b1 = __shfl(acc1, lane + 16), c1v = __shfl(acc1, lane + 32);
        float b2 = __shfl(acc2, lane + 16), c2v = __shfl(acc2, lane + 32);
        float b3 = __shfl(acc3, lane + 16), c3v = __shfl(acc3, lane + 32);
        float mm0 = (acc0 + b0 + c0v) * (1.f / 3.f);
        float mm1 = (acc1 + b1 + c1v) * (1.f / 3.f);
        float mm2 = (acc2 + b2 + c2v) * (1.f / 3.f);
        float mm3 = (acc3 + b3 + c3v) * (1.f / 3.f);
        float ss = (lane < 16) ? (mm0*mm0 + mm1*mm1 + mm2*mm2 + mm3*mm3) : 0.f;
        #pragma unroll
        for (int o = 1; o < 16; o <<= 1) ss += __shfl_xor(ss, o);
        float nrm = sqrtf(ss);
        float invn = 1.f / fmaxf(nrm, EPSF);
        if (lane < 16) {
            ((float4*)outv)[(size_t)n * 16 + lane] =
                make_float4(mm0 * invn, mm1 * invn, mm2 * invn, mm3 * invn);
        }
    }
}

extern "C" void kernel_launch(void* const* d_in, const int* in_sizes, int n_in,
                              void* d_out, int out_size, void* d_ws, size_t ws_size,
                              hipStream_t stream)
{
    const float* x     = (const float*)d_in[0];
    const int*   src   = (const int*)d_in[1];
    const int*   dst   = (const int*)d_in[2];
    const int*   efeat = (const int*)d_in[3];
    const float* W1    = (const float*)d_in[4];
    const float* Eemb1 = (const float*)d_in[5];
    const float* We1   = (const float*)d_in[6];
    const float* al1   = (const float*)d_in[7];
    const float* ar1   = (const float*)d_in[8];
    const float* ae1   = (const float*)d_in[9];
    const float* W2    = (const float*)d_in[10];
    const float* Eemb2 = (const float*)d_in[11];
    const float* We2   = (const float*)d_in[12];
    const float* al2   = (const float*)d_in[13];
    const float* ar2   = (const float*)d_in[14];
    const float* ae2   = (const float*)d_in[15];
    const float* Wres2 = (const float*)d_in[16];

    char* w = (char*)d_ws;
    auto alloc = [&](size_t bytes) {
        char* p = w;
        w += (bytes + 255) & ~(size_t)255;
        return p;
    };
    ushort* featb = (ushort*)alloc((size_t)NN * FEAT * 2);   // gemm out (bf16)
    ushort* h1b   = (ushort*)alloc((size_t)NN * FEAT * 2);   // layer1 out (bf16)
    ushort* resb  = (ushort*)alloc((size_t)NN * FEAT * 2);   // residual (bf16)
    float4* el4   = (float4*)alloc((size_t)NN * 16);
    float4* er4   = (float4*)alloc((size_t)NN * 16);
    int*    deg   = (int*)alloc((size_t)NN * 4);
    int*    off   = (int*)alloc((size_t)(NN + 1) * 4);
    int*    cur   = (int*)alloc((size_t)NN * 4);
    int*    srcP  = (int*)alloc((size_t)EEN * 4);
    int*    bsum  = (int*)alloc(64 * 4);
    int*    bexc  = (int*)alloc(64 * 4);
    ushort* w1bt  = (ushort*)alloc((size_t)FEAT * INF_ * 2);
    ushort* w2bt  = (ushort*)alloc((size_t)FEAT * FEAT * 2);
    ushort* wrbt  = (ushort*)alloc((size_t)FEAT * FEAT * 2);
    float*  ee1   = (float*)alloc(24 * 4);
    float*  ee2   = (float*)alloc(24 * 4);

    hipMemsetAsync(deg, 0, (size_t)NN * 4, stream);

    const int eb = (EEN + 255) / 256;
    k_hist<<<eb, 256, 0, stream>>>(dst, deg);
    k_scan1<<<NB, 1024, 0, stream>>>(deg, off, bsum);
    k_scan2<<<1, 64, 0, stream>>>(bsum, bexc, off);
    k_scan3<<<NB, 1024, 0, stream>>>(off, cur, bexc);
    k_scatter<<<eb, 256, 0, stream>>>(src, dst, efeat, cur, srcP);
    k_prep<<<122, 256, 0, stream>>>(W1, w1bt, W2, w2bt, Wres2, wrbt,
            Eemb1, We1, ae1, ee1, Eemb2, We2, ae2, ee2);

    const int nb4 = (NN + 3) / 4;
    // ---- layer 1 ----
    gemm_mfma1<<<(NN + 127) / 128, 256, 0, stream>>>(x, w1bt, featb,
            el4, er4, al1, ar1, NN, INF_);
    k_attn_agg<false, false><<<nb4, 256, 0, stream>>>(off, srcP, el4, er4, ee1,
            featb, nullptr, h1b);
    // ---- layer 2 (W2 and Wres in one pass) ----
    gemm_mfma2<<<(NN + 63) / 64, 256, 0, stream>>>(h1b, w2bt, wrbt, featb,
            resb, el4, er4, al2, ar2, NN, FEAT);
    k_attn_agg<true, true><<<nb4, 256, 0, stream>>>(off, srcP, el4, er4, ee2,
            featb, resb, (float*)d_out);
}

// Round 11
// 219.893 us; speedup vs baseline: 1.2250x; 1.2250x over previous
//
#include <hip/hip_runtime.h>
#include <cstdint>
#include <cstddef>

#define NN   50000
#define EEN  800000
#define INF_ 256
#define HH   3
#define FEAT 192   // H*D
#define EFD  64
#define NEG_ 0.2f
#define EPSF 1e-12f
#define SMASK 0x0FFFFFF0   // s*16 field in srcP
#define NBK  49            // buckets = dst>>10
#define BKSTR 20480        // per-bucket capacity (mean 16384, +32 sigma)
#define CHUNK 3125         // edges per pass-A block (256*3125 = 800000)

typedef __attribute__((ext_vector_type(8))) short short8;
typedef __attribute__((ext_vector_type(4))) float f32x4;
typedef __attribute__((ext_vector_type(2))) float f32x2;

static __device__ __forceinline__ float4 ld4(const float* p) {
    return *reinterpret_cast<const float4*>(p);
}
static __device__ __forceinline__ uint f2b(float f) {
    union { float f; uint32_t u; } v; v.f = f;
    uint32_t u = v.u;
    return (u + 0x7FFFu + ((u >> 16) & 1u)) >> 16;
}
static __device__ __forceinline__ uint pack2(float a, float b) {
    return f2b(a) | (f2b(b) << 16);
}
static __device__ __forceinline__ float blo(uint u) {
    return __uint_as_float(u << 16);
}
static __device__ __forceinline__ float bhi(uint u) {
    return __uint_as_float(u & 0xFFFF0000u);
}

// ---------------- prep: weight transposes (blocks 0..119) + eetab (120,121) --
static __device__ __forceinline__ void trans_tile(const float* __restrict__ W,
        ushort* __restrict__ BT, int K, int N, int kt, int nt)
{
    __shared__ float tile[32][33];
    const int tx = threadIdx.x & 31, ty = threadIdx.x >> 5;  // 32 x 8
    #pragma unroll
    for (int r = 0; r < 4; ++r) {
        int row = kt * 32 + ty + r * 8;
        int col = nt * 32 + tx;
        tile[ty + r * 8][tx] = W[(size_t)row * N + col];
    }
    __syncthreads();
    #pragma unroll
    for (int r = 0; r < 4; ++r) {
        int n = nt * 32 + ty + r * 8;
        int k = kt * 32 + tx;
        BT[(size_t)n * K + k] = (ushort)f2b(tile[tx][ty + r * 8]);
    }
}

static __device__ __forceinline__ void eetab_calc(const float* __restrict__ Eemb,
        const float* __restrict__ We, const float* __restrict__ ae,
        float* __restrict__ eetab)
{
    __shared__ float t1[3 * 64];
    const int t = threadIdx.x;
    if (t < 192) {
        const int g = t & 63, h = t >> 6;
        const float* wrow = We + g * FEAT + h * EFD;
        const float* av   = ae + h * EFD;
        float s = 0.f;
        #pragma unroll 8
        for (int f = 0; f < EFD; ++f) s += wrow[f] * av[f];
        t1[h * 64 + g] = s;
    }
    __syncthreads();
    if (t < 24) {
        int tt = t / 3, hh = t - tt * 3;
        float acc = 0.f;
        const float* em = Eemb + tt * EFD;
        const float* tv = t1 + hh * 64;
        #pragma unroll 8
        for (int g2 = 0; g2 < 64; ++g2) acc += em[g2] * tv[g2];
        eetab[tt * 3 + hh] = acc;
    }
}

__global__ __launch_bounds__(256) void k_prep(const float* __restrict__ W1,
        ushort* __restrict__ o1, const float* __restrict__ W2,
        ushort* __restrict__ o2, const float* __restrict__ W3,
        ushort* __restrict__ o3,
        const float* __restrict__ Eemb1, const float* __restrict__ We1,
        const float* __restrict__ ae1, float* __restrict__ ee1,
        const float* __restrict__ Eemb2, const float* __restrict__ We2,
        const float* __restrict__ ae2, float* __restrict__ ee2)
{
    int b = blockIdx.x;
    if (b < 48) {            // W1: K=256 (8 ktiles) x N=192 (6 ntiles)
        trans_tile(W1, o1, INF_, FEAT, b & 7, b >> 3);
    } else if (b < 84) {     // W2: 6 x 6
        int i = b - 48;
        trans_tile(W2, o2, FEAT, FEAT, i % 6, i / 6);
    } else if (b < 120) {    // W3: 6 x 6
        int i = b - 84;
        trans_tile(W3, o3, FEAT, FEAT, i % 6, i / 6);
    } else if (b == 120) {
        eetab_calc(Eemb1, We1, ae1, ee1);
    } else {
        eetab_calc(Eemb2, We2, ae2, ee2);
    }
}

// ---------------- GEMM1: 128-row tile, full-N(192), fused el/er --------------
#define LDA 40   // padded LDS row stride (ushort)
__global__ __launch_bounds__(256) void gemm_mfma1(const float* __restrict__ A,
        const ushort* __restrict__ BT, ushort* __restrict__ Cb,
        float4* __restrict__ el4, float4* __restrict__ er4,
        const float* __restrict__ al, const float* __restrict__ ar,
        int M, int K)
{
    __shared__ ushort As[128 * LDA];
    __shared__ ushort Bs[192 * LDA];
    const int t = threadIdx.x;
    const int lane = t & 63, w = t >> 6;
    const int bm = blockIdx.x * 128;
    const int fr = lane & 15;
    const int fq = lane >> 4;
    const int fg = fq * 8;
    const int arow = t >> 1;           // 0..127
    const int acol = (t & 1) * 8;      // 0 or 8 (plus +16 later)
    const int brow = t >> 2;           // 0..63
    const int bcol = (t & 3) * 8;

    f32x4 acc[2][12];
    #pragma unroll
    for (int i = 0; i < 2; ++i)
        #pragma unroll
        for (int c = 0; c < 12; ++c)
            acc[i][c] = (f32x4){0.f, 0.f, 0.f, 0.f};

    const int ga = bm + arow;
    for (int k0 = 0; k0 < K; k0 += 32) {
        uint4 u0 = make_uint4(0,0,0,0), u1 = u0;
        if (ga < M) {
            const float* ap = A + (size_t)ga * K + k0 + acol;
            float4 f0 = ld4(ap), f1 = ld4(ap + 4);
            float4 f2v = ld4(ap + 16), f3 = ld4(ap + 20);
            u0 = make_uint4(pack2(f0.x,f0.y), pack2(f0.z,f0.w),
                            pack2(f1.x,f1.y), pack2(f1.z,f1.w));
            u1 = make_uint4(pack2(f2v.x,f2v.y), pack2(f2v.z,f2v.w),
                            pack2(f3.x,f3.y), pack2(f3.z,f3.w));
        }
        *reinterpret_cast<uint4*>(As + arow * LDA + acol) = u0;
        *reinterpret_cast<uint4*>(As + arow * LDA + acol + 16) = u1;
        #pragma unroll
        for (int j = 0; j < 3; ++j) {
            uint4 bv = *reinterpret_cast<const uint4*>(BT + (size_t)(j * 64 + brow) * K + k0 + bcol);
            *reinterpret_cast<uint4*>(Bs + (j * 64 + brow) * LDA + bcol) = bv;
        }
        __syncthreads();
        short8 afr0 = *reinterpret_cast<const short8*>(As + (w * 32 + fr) * LDA + fg);
        short8 afr1 = *reinterpret_cast<const short8*>(As + (w * 32 + 16 + fr) * LDA + fg);
        #pragma unroll
        for (int c = 0; c < 12; ++c) {
            short8 bfr = *reinterpret_cast<const short8*>(Bs + (c * 16 + fr) * LDA + fg);
            acc[0][c] = __builtin_amdgcn_mfma_f32_16x16x32_bf16(afr0, bfr, acc[0][c], 0, 0, 0);
            acc[1][c] = __builtin_amdgcn_mfma_f32_16x16x32_bf16(afr1, bfr, acc[1][c], 0, 0, 0);
        }
        __syncthreads();
    }
    #pragma unroll
    for (int i = 0; i < 2; ++i) {
        #pragma unroll
        for (int j = 0; j < 4; ++j) {
            int row = bm + w * 32 + i * 16 + fq * 4 + j;
            if (row < M) {
                #pragma unroll
                for (int c = 0; c < 12; ++c)
                    Cb[(size_t)row * FEAT + c * 16 + fr] = (ushort)f2b(acc[i][c][j]);
            }
        }
    }
    float alv[12], arv[12];
    #pragma unroll
    for (int c = 0; c < 12; ++c) {
        alv[c] = al[c * 16 + fr];
        arv[c] = ar[c * 16 + fr];
    }
    #pragma unroll
    for (int i = 0; i < 2; ++i) {
        #pragma unroll
        for (int j = 0; j < 4; ++j) {
            int row = bm + w * 32 + i * 16 + fq * 4 + j;
            float pl0 = 0.f, pl1 = 0.f, pl2 = 0.f;
            float pr0 = 0.f, pr1 = 0.f, pr2 = 0.f;
            #pragma unroll
            for (int c = 0; c < 4; ++c)  { pl0 += acc[i][c][j]*alv[c];  pr0 += acc[i][c][j]*arv[c]; }
            #pragma unroll
            for (int c = 4; c < 8; ++c)  { pl1 += acc[i][c][j]*alv[c];  pr1 += acc[i][c][j]*arv[c]; }
            #pragma unroll
            for (int c = 8; c < 12; ++c) { pl2 += acc[i][c][j]*alv[c];  pr2 += acc[i][c][j]*arv[c]; }
            #pragma unroll
            for (int o = 1; o < 16; o <<= 1) {
                pl0 += __shfl_xor(pl0, o); pl1 += __shfl_xor(pl1, o); pl2 += __shfl_xor(pl2, o);
                pr0 += __shfl_xor(pr0, o); pr1 += __shfl_xor(pr1, o); pr2 += __shfl_xor(pr2, o);
            }
            if (fr == 0 && row < M) {
                el4[row] = make_float4(pl0, pl1, pl2, 0.f);
                er4[row] = make_float4(pr0, pr1, pr2, 0.f);
            }
        }
    }
}

// ---------------- GEMM2: 64-row tile, dual-B, fused el/er --------------------
__global__ __launch_bounds__(256) void gemm_mfma2(const ushort* __restrict__ A,
        const ushort* __restrict__ BT, const ushort* __restrict__ BT2,
        ushort* __restrict__ Cb, ushort* __restrict__ resb,
        float4* __restrict__ el4, float4* __restrict__ er4,
        const float* __restrict__ al, const float* __restrict__ ar,
        int M, int K)
{
    __shared__ ushort As[64 * LDA];
    __shared__ ushort Bs[192 * LDA];
    __shared__ ushort Bs2[192 * LDA];
    const int t = threadIdx.x;
    const int lane = t & 63, w = t >> 6;
    const int bm = blockIdx.x * 64;
    const int fr = lane & 15;
    const int fq = lane >> 4;
    const int fg = fq * 8;
    const int arow = t >> 2;           // 0..63
    const int acol = (t & 3) * 8;
    const int brow = t >> 2;
    const int bcol = (t & 3) * 8;

    f32x4 acc[12], acc2[12];
    #pragma unroll
    for (int c = 0; c < 12; ++c) {
        acc[c] = (f32x4){0.f, 0.f, 0.f, 0.f};
        acc2[c] = (f32x4){0.f, 0.f, 0.f, 0.f};
    }

    const int ga = bm + arow;
    for (int k0 = 0; k0 < K; k0 += 32) {
        uint4 u0 = make_uint4(0,0,0,0);
        if (ga < M)
            u0 = *reinterpret_cast<const uint4*>(A + (size_t)ga * K + k0 + acol);
        *reinterpret_cast<uint4*>(As + arow * LDA + acol) = u0;
        #pragma unroll
        for (int j = 0; j < 3; ++j) {
            uint4 bv = *reinterpret_cast<const uint4*>(BT + (size_t)(j * 64 + brow) * K + k0 + bcol);
            *reinterpret_cast<uint4*>(Bs + (j * 64 + brow) * LDA + bcol) = bv;
            uint4 b2 = *reinterpret_cast<const uint4*>(BT2 + (size_t)(j * 64 + brow) * K + k0 + bcol);
            *reinterpret_cast<uint4*>(Bs2 + (j * 64 + brow) * LDA + bcol) = b2;
        }
        __syncthreads();
        short8 afr = *reinterpret_cast<const short8*>(As + (w * 16 + fr) * LDA + fg);
        #pragma unroll
        for (int c = 0; c < 12; ++c) {
            short8 bfr = *reinterpret_cast<const short8*>(Bs + (c * 16 + fr) * LDA + fg);
            acc[c] = __builtin_amdgcn_mfma_f32_16x16x32_bf16(afr, bfr, acc[c], 0, 0, 0);
            short8 b2 = *reinterpret_cast<const short8*>(Bs2 + (c * 16 + fr) * LDA + fg);
            acc2[c] = __builtin_amdgcn_mfma_f32_16x16x32_bf16(afr, b2, acc2[c], 0, 0, 0);
        }
        __syncthreads();
    }
    #pragma unroll
    for (int j = 0; j < 4; ++j) {
        int row = bm + w * 16 + fq * 4 + j;
        if (row < M) {
            #pragma unroll
            for (int c = 0; c < 12; ++c) {
                Cb[(size_t)row * FEAT + c * 16 + fr] = (ushort)f2b(acc[c][j]);
                resb[(size_t)row * FEAT + c * 16 + fr] = (ushort)f2b(acc2[c][j]);
            }
        }
    }
    float alv[12], arv[12];
    #pragma unroll
    for (int c = 0; c < 12; ++c) {
        alv[c] = al[c * 16 + fr];
        arv[c] = ar[c * 16 + fr];
    }
    #pragma unroll
    for (int j = 0; j < 4; ++j) {
        int row = bm + w * 16 + fq * 4 + j;
        float pl0 = 0.f, pl1 = 0.f, pl2 = 0.f;
        float pr0 = 0.f, pr1 = 0.f, pr2 = 0.f;
        #pragma unroll
        for (int c = 0; c < 4; ++c)  { pl0 += acc[c][j]*alv[c];  pr0 += acc[c][j]*arv[c]; }
        #pragma unroll
        for (int c = 4; c < 8; ++c)  { pl1 += acc[c][j]*alv[c];  pr1 += acc[c][j]*arv[c]; }
        #pragma unroll
        for (int c = 8; c < 12; ++c) { pl2 += acc[c][j]*alv[c];  pr2 += acc[c][j]*arv[c]; }
        #pragma unroll
        for (int o = 1; o < 16; o <<= 1) {
            pl0 += __shfl_xor(pl0, o); pl1 += __shfl_xor(pl1, o); pl2 += __shfl_xor(pl2, o);
            pr0 += __shfl_xor(pr0, o); pr1 += __shfl_xor(pr1, o); pr2 += __shfl_xor(pr2, o);
        }
        if (fr == 0 && row < M) {
            el4[row] = make_float4(pl0, pl1, pl2, 0.f);
            er4[row] = make_float4(pr0, pr1, pr2, 0.f);
        }
    }
}

// ---------------- CSR build: two-pass LDS-bucketed counting sort -------------
// rec = src(16) | et(3)<<16 | dst_lo10(10)<<19
__global__ __launch_bounds__(256) void k_bucketA(const int* __restrict__ src,
        const int* __restrict__ dst, const int* __restrict__ et,
        int* __restrict__ bcnt, uint* __restrict__ bko)
{
    __shared__ uint recs[CHUNK];
    __shared__ ushort abk[CHUNK];
    __shared__ int hcnt[NBK], hoff[NBK], hcur[NBK], gb[NBK];
    const int t = threadIdx.x;
    const int e0 = blockIdx.x * CHUNK;
    if (t < NBK) hcnt[t] = 0;
    __syncthreads();
    uint rec[13];
    int  bk[13];
    #pragma unroll
    for (int k = 0; k < 13; ++k) {
        int i = t + k * 256;
        if (i < CHUNK) {
            int e = e0 + i;
            int s = src[e], d = dst[e], tt = et[e];
            rec[k] = (uint)s | ((uint)tt << 16) | ((uint)(d & 1023) << 19);
            bk[k] = d >> 10;
            atomicAdd(&hcnt[bk[k]], 1);
        } else {
            bk[k] = -1;
        }
    }
    __syncthreads();
    if (t < 64) {
        int v = (t < NBK) ? hcnt[t] : 0;
        int incl = v;
        #pragma unroll
        for (int o = 1; o < 64; o <<= 1) {
            int u = __shfl_up(incl, o);
            if (t >= o) incl += u;
        }
        if (t < NBK) { hoff[t] = incl - v; hcur[t] = incl - v; }
    }
    __syncthreads();
    #pragma unroll
    for (int k = 0; k < 13; ++k) {
        if (bk[k] >= 0) {
            int p = atomicAdd(&hcur[bk[k]], 1);
            recs[p] = rec[k];
            abk[p] = (ushort)bk[k];
        }
    }
    __syncthreads();
    if (t < NBK) gb[t] = atomicAdd(&bcnt[t], hcnt[t]);
    __syncthreads();
    for (int i = t; i < CHUNK; i += 256) {
        int b = abk[i];
        bko[(size_t)b * BKSTR + gb[b] + (i - hoff[b])] = recs[i];
    }
}

__global__ __launch_bounds__(64) void k_scanB(const int* __restrict__ bcnt,
        int* __restrict__ bexc, int* __restrict__ off)
{
    int t = threadIdx.x;
    int v = (t < NBK) ? bcnt[t] : 0;
    int incl = v;
    #pragma unroll
    for (int o = 1; o < 64; o <<= 1) {
        int u = __shfl_up(incl, o);
        if (t >= o) incl += u;
    }
    if (t < NBK) bexc[t] = incl - v;
    if (t == 63) off[NN] = incl;
}

__global__ __launch_bounds__(256) void k_bucketB(const int* __restrict__ bcnt,
        const int* __restrict__ bexc, const uint* __restrict__ bko,
        int* __restrict__ off, int* __restrict__ srcP)
{
    __shared__ int ldeg[1024], loff[1024];
    __shared__ int wsum[4];
    const int t = threadIdx.x, b = blockIdx.x;
    const int nd0 = b << 10;
    const int ncnt = min(1024, NN - nd0);
    const int ecnt = bcnt[b];
    const int base = bexc[b];
    const uint* rp = bko + (size_t)b * BKSTR;
    for (int i = t; i < 1024; i += 256) ldeg[i] = 0;
    __syncthreads();
    for (int i = t; i < ecnt; i += 256)
        atomicAdd(&ldeg[rp[i] >> 19], 1);
    __syncthreads();
    {
        int a0 = ldeg[4*t], a1 = ldeg[4*t+1], a2 = ldeg[4*t+2], a3 = ldeg[4*t+3];
        int s = a0 + a1 + a2 + a3;
        int incl = s;
        const int lane = t & 63;
        #pragma unroll
        for (int o = 1; o < 64; o <<= 1) {
            int u = __shfl_up(incl, o);
            if (lane >= o) incl += u;
        }
        int wid = t >> 6;
        if (lane == 63) wsum[wid] = incl;
        __syncthreads();
        int wb = 0;
        #pragma unroll
        for (int q = 0; q < 4; ++q) if (q < wid) wb += wsum[q];
        int tb = wb + incl - s;
        loff[4*t] = tb; loff[4*t+1] = tb + a0;
        loff[4*t+2] = tb + a0 + a1; loff[4*t+3] = tb + a0 + a1 + a2;
    }
    __syncthreads();
    for (int i = t; i < ncnt; i += 256) off[nd0 + i] = base + loff[i];
    for (int i = t; i < 1024; i += 256) ldeg[i] = loff[i];
    __syncthreads();
    for (int i = t; i < ecnt; i += 256) {
        uint rec = rp[i];
        int ld = rec >> 19;
        int p = base + atomicAdd(&ldeg[ld], 1);
        srcP[p] = (int)(((rec & 0xFFFFu) << 4) | (((rec >> 16) & 7u) << 28));
    }
}

// ---------------- fused edge-softmax + aggregation (wave per node) -----------
#define EXTRACT(U, V01, V23) \
    f32x2 V01 = {blo((U).x), bhi((U).x)}; \
    f32x2 V23 = {blo((U).y), bhi((U).y)};

template<bool RES, bool FINAL>
__global__ __launch_bounds__(256) void k_attn_agg(const int* __restrict__ off,
        const int* __restrict__ srcP, const float4* __restrict__ el4,
        const float4* __restrict__ er4, const float* __restrict__ eetab,
        const ushort* __restrict__ featb, const ushort* __restrict__ resb,
        void* __restrict__ outv)
{
    __shared__ float shw[4][64 * 6];
    __shared__ float eet[24];
    const int wid = threadIdx.x >> 6, lane = threadIdx.x & 63;
    if (threadIdx.x < 24) eet[threadIdx.x] = eetab[threadIdx.x];
    __syncthreads();
    const int n = blockIdx.x * 4 + wid;
    if (n >= NN) return;
    const int hd = lane >> 4;                  // 0..2 gather head; 3 = idle
    const char* elc = (const char*)el4;
    const char* fb  = (const char*)featb + lane * 8;
    float* sw = shw[wid];

    const int beg = off[n], end = off[n + 1];
    const float4 erv = er4[n];
    f32x2 acc01 = {0.f, 0.f}, acc23 = {0.f, 0.f};
    float dl0 = 0.f, dl1 = 0.f, dl2 = 0.f;

    for (int c0 = beg; c0 < end; c0 += 64) {
        const int e = c0 + lane;
        float p0 = 0.f, p1 = 0.f, p2 = 0.f;
        int boff = 0;
        if (e < end) {
            int sp = srcP[e];
            int s16 = sp & SMASK;
            int tt = ((unsigned)sp) >> 28;
            float4 ev = *reinterpret_cast<const float4*>(elc + s16);
            float l0 = ev.x + erv.x + eet[tt*3+0];
            float l1 = ev.y + erv.y + eet[tt*3+1];
            float l2 = ev.z + erv.z + eet[tt*3+2];
            l0 = l0 > 0.f ? l0 : NEG_ * l0;
            l1 = l1 > 0.f ? l1 : NEG_ * l1;
            l2 = l2 > 0.f ? l2 : NEG_ * l2;
            p0 = __expf(l0); p1 = __expf(l1); p2 = __expf(l2);
            boff = s16 * 24;                   // s*384 bytes into featb
        }
        dl0 += p0; dl1 += p1; dl2 += p2;
        const float bf = __int_as_float(boff);
        float* sl = sw + lane * 6;
        *reinterpret_cast<float2*>(sl + 0) = make_float2(p0, bf);
        *reinterpret_cast<float2*>(sl + 2) = make_float2(p1, bf);
        *reinterpret_cast<float2*>(sl + 4) = make_float2(p2, bf);
        const int cnt = min(64, end - c0);
        const float* swh = sw + hd * 2;
        int j = 0;
        for (; j + 4 <= cnt; j += 4) {
            if (lane < 48) {
                float2 g0 = *reinterpret_cast<const float2*>(swh + (j+0)*6);
                float2 g1 = *reinterpret_cast<const float2*>(swh + (j+1)*6);
                float2 g2 = *reinterpret_cast<const float2*>(swh + (j+2)*6);
                float2 g3 = *reinterpret_cast<const float2*>(swh + (j+3)*6);
                uint2 u0 = *reinterpret_cast<const uint2*>(fb + __float_as_int(g0.y));
                uint2 u1 = *reinterpret_cast<const uint2*>(fb + __float_as_int(g1.y));
                uint2 u2 = *reinterpret_cast<const uint2*>(fb + __float_as_int(g2.y));
                uint2 u3 = *reinterpret_cast<const uint2*>(fb + __float_as_int(g3.y));
                EXTRACT(u0, a01, a23)
                EXTRACT(u1, b01, b23)
                EXTRACT(u2, c01, c23)
                EXTRACT(u3, d01, d23)
                acc01 += g0.x * a01; acc23 += g0.x * a23;
                acc01 += g1.x * b01; acc23 += g1.x * b23;
                acc01 += g2.x * c01; acc23 += g2.x * c23;
                acc01 += g3.x * d01; acc23 += g3.x * d23;
            }
        }
        for (; j < cnt; ++j) {
            if (lane < 48) {
                float2 gv = *reinterpret_cast<const float2*>(swh + j*6);
                uint2 uu = *reinterpret_cast<const uint2*>(fb + __float_as_int(gv.y));
                EXTRACT(uu, v01, v23)
                acc01 += gv.x * v01; acc23 += gv.x * v23;
            }
        }
    }
    #pragma unroll
    for (int o = 32; o > 0; o >>= 1) {
        dl0 += __shfl_xor(dl0, o);
        dl1 += __shfl_xor(dl1, o);
        dl2 += __shfl_xor(dl2, o);
    }
    const float den = hd == 0 ? dl0 : (hd == 1 ? dl1 : dl2);
    const float inv = 1.f / fmaxf(den, EPSF);
    float acc0 = acc01.x * inv, acc1 = acc01.y * inv;
    float acc2 = acc23.x * inv, acc3 = acc23.y * inv;
    if (RES) {
        if (lane < 48) {
            uint2 r = *reinterpret_cast<const uint2*>((const char*)resb + (size_t)n * 384 + lane * 8);
            acc0 += blo(r.x); acc1 += bhi(r.x);
            acc2 += blo(r.y); acc3 += bhi(r.y);
        }
    }
    acc0 = acc0 > 0.f ? acc0 : expm1f(acc0);
    acc1 = acc1 > 0.f ? acc1 : expm1f(acc1);
    acc2 = acc2 > 0.f ? acc2 : expm1f(acc2);
    acc3 = acc3 > 0.f ? acc3 : expm1f(acc3);
    if (!FINAL) {
        if (lane < 48) {
            ushort4 o4;
            o4.x = (ushort)f2b(acc0); o4.y = (ushort)f2b(acc1);
            o4.z = (ushort)f2b(acc2); o4.w = (ushort)f2b(acc3);
            ((ushort4*)outv)[(size_t)n * 48 + lane] = o4;
        }
    } else {
        float b0 = __shfl(acc0, lane + 16), c0v = __shfl(acc0, lane + 32);
        float b1 = __shfl(acc1, lane + 16), c1v = __shfl(acc1, lane + 32);
        float b2 = __shfl(acc2, lane + 16), c2v = __shfl(acc2, lane + 32);
        float b3 = __shfl(acc3, lane + 16), c3v = __shfl(acc3, lane + 32);
        float mm0 = (acc0 + b0 + c0v) * (1.f / 3.f);
        float mm1 = (acc1 + b1 + c1v) * (1.f / 3.f);
        float mm2 = (acc2 + b2 + c2v) * (1.f / 3.f);
        float mm3 = (acc3 + b3 + c3v) * (1.f / 3.f);
        float ss = (lane < 16) ? (mm0*mm0 + mm1*mm1 + mm2*mm2 + mm3*mm3) : 0.f;
        #pragma unroll
        for (int o = 1; o < 16; o <<= 1) ss += __shfl_xor(ss, o);
        float nrm = sqrtf(ss);
        float invn = 1.f / fmaxf(nrm, EPSF);
        if (lane < 16) {
            ((float4*)outv)[(size_t)n * 16 + lane] =
                make_float4(mm0 * invn, mm1 * invn, mm2 * invn, mm3 * invn);
        }
    }
}

extern "C" void kernel_launch(void* const* d_in, const int* in_sizes, int n_in,
                              void* d_out, int out_size, void* d_ws, size_t ws_size,
                              hipStream_t stream)
{
    const float* x     = (const float*)d_in[0];
    const int*   src   = (const int*)d_in[1];
    const int*   dst   = (const int*)d_in[2];
    const int*   efeat = (const int*)d_in[3];
    const float* W1    = (const float*)d_in[4];
    const float* Eemb1 = (const float*)d_in[5];
    const float* We1   = (const float*)d_in[6];
    const float* al1   = (const float*)d_in[7];
    const float* ar1   = (const float*)d_in[8];
    const float* ae1   = (const float*)d_in[9];
    const float* W2    = (const float*)d_in[10];
    const float* Eemb2 = (const float*)d_in[11];
    const float* We2   = (const float*)d_in[12];
    const float* al2   = (const float*)d_in[13];
    const float* ar2   = (const float*)d_in[14];
    const float* ae2   = (const float*)d_in[15];
    const float* Wres2 = (const float*)d_in[16];

    char* w = (char*)d_ws;
    auto alloc = [&](size_t bytes) {
        char* p = w;
        w += (bytes + 255) & ~(size_t)255;
        return p;
    };
    ushort* featb = (ushort*)alloc((size_t)NN * FEAT * 2);   // gemm out (bf16)
    ushort* h1b   = (ushort*)alloc((size_t)NN * FEAT * 2);   // layer1 out (bf16)
    ushort* resb  = (ushort*)alloc((size_t)NN * FEAT * 2);   // residual (bf16)
    float4* el4   = (float4*)alloc((size_t)NN * 16);
    float4* er4   = (float4*)alloc((size_t)NN * 16);
    int*    off   = (int*)alloc((size_t)(NN + 1) * 4);
    int*    srcP  = (int*)alloc((size_t)EEN * 4);
    uint*   bko   = (uint*)alloc((size_t)NBK * BKSTR * 4);
    int*    bcnt  = (int*)alloc(64 * 4);
    int*    bexc  = (int*)alloc(64 * 4);
    ushort* w1bt  = (ushort*)alloc((size_t)FEAT * INF_ * 2);
    ushort* w2bt  = (ushort*)alloc((size_t)FEAT * FEAT * 2);
    ushort* wrbt  = (ushort*)alloc((size_t)FEAT * FEAT * 2);
    float*  ee1   = (float*)alloc(24 * 4);
    float*  ee2   = (float*)alloc(24 * 4);

    hipMemsetAsync(bcnt, 0, 64 * 4, stream);

    // CSR build (bucketed counting sort)
    k_bucketA<<<EEN / CHUNK, 256, 0, stream>>>(src, dst, efeat, bcnt, bko);
    k_scanB<<<1, 64, 0, stream>>>(bcnt, bexc, off);
    k_bucketB<<<NBK, 256, 0, stream>>>(bcnt, bexc, bko, off, srcP);
    k_prep<<<122, 256, 0, stream>>>(W1, w1bt, W2, w2bt, Wres2, wrbt,
            Eemb1, We1, ae1, ee1, Eemb2, We2, ae2, ee2);

    const int nb4 = (NN + 3) / 4;
    // ---- layer 1 ----
    gemm_mfma1<<<(NN + 127) / 128, 256, 0, stream>>>(x, w1bt, featb,
            el4, er4, al1, ar1, NN, INF_);
    k_attn_agg<false, false><<<nb4, 256, 0, stream>>>(off, srcP, el4, er4, ee1,
            featb, nullptr, h1b);
    // ---- layer 2 (W2 and Wres in one pass) ----
    gemm_mfma2<<<(NN + 63) / 64, 256, 0, stream>>>(h1b, w2bt, wrbt, featb,
            resb, el4, er4, al2, ar2, NN, FEAT);
    k_attn_agg<true, true><<<nb4, 256, 0, stream>>>(off, srcP, el4, er4, ee2,
            featb, resb, (float*)d_out);
}

// Round 12
// 214.253 us; speedup vs baseline: 1.2573x; 1.0263x over previous
//
#include <hip/hip_runtime.h>
#include <cstdint>
#include <cstddef>

#define NN   50000
#define EEN  800000
#define INF_ 256
#define HH   3
#define FEAT 192   // H*D
#define EFD  64
#define NEG_ 0.2f
#define EPSF 1e-12f
#define SMASK 0x0FFFFFF0   // s*16 field in srcP
#define NBK  49            // buckets = dst>>10
#define BKSTR 20480        // per-bucket capacity
#define CHUNK 3125         // edges per pass-A block

typedef __attribute__((ext_vector_type(8))) short short8;
typedef __attribute__((ext_vector_type(4))) float f32x4;
typedef __attribute__((ext_vector_type(2))) float f32x2;

static __device__ __forceinline__ float4 ld4(const float* p) {
    return *reinterpret_cast<const float4*>(p);
}
static __device__ __forceinline__ uint f2b(float f) {
    union { float f; uint32_t u; } v; v.f = f;
    uint32_t u = v.u;
    return (u + 0x7FFFu + ((u >> 16) & 1u)) >> 16;
}
static __device__ __forceinline__ uint pack2(float a, float b) {
    return f2b(a) | (f2b(b) << 16);
}
static __device__ __forceinline__ float blo(uint u) {
    return __uint_as_float(u << 16);
}
static __device__ __forceinline__ float bhi(uint u) {
    return __uint_as_float(u & 0xFFFF0000u);
}

// ---------------- prep: weight transposes (blocks 0..119) + eetab (120,121) --
static __device__ __forceinline__ void trans_tile(const float* __restrict__ W,
        ushort* __restrict__ BT, int K, int N, int kt, int nt)
{
    __shared__ float tile[32][33];
    const int tx = threadIdx.x & 31, ty = threadIdx.x >> 5;  // 32 x 8
    #pragma unroll
    for (int r = 0; r < 4; ++r) {
        int row = kt * 32 + ty + r * 8;
        int col = nt * 32 + tx;
        tile[ty + r * 8][tx] = W[(size_t)row * N + col];
    }
    __syncthreads();
    #pragma unroll
    for (int r = 0; r < 4; ++r) {
        int n = nt * 32 + ty + r * 8;
        int k = kt * 32 + tx;
        BT[(size_t)n * K + k] = (ushort)f2b(tile[tx][ty + r * 8]);
    }
}

static __device__ __forceinline__ void eetab_calc(const float* __restrict__ Eemb,
        const float* __restrict__ We, const float* __restrict__ ae,
        float* __restrict__ eetab)
{
    __shared__ float t1[3 * 64];
    const int t = threadIdx.x;
    if (t < 192) {
        const int g = t & 63, h = t >> 6;
        const float* wrow = We + g * FEAT + h * EFD;
        const float* av   = ae + h * EFD;
        float s = 0.f;
        #pragma unroll 8
        for (int f = 0; f < EFD; ++f) s += wrow[f] * av[f];
        t1[h * 64 + g] = s;
    }
    __syncthreads();
    if (t < 24) {
        int tt = t / 3, hh = t - tt * 3;
        float acc = 0.f;
        const float* em = Eemb + tt * EFD;
        const float* tv = t1 + hh * 64;
        #pragma unroll 8
        for (int g2 = 0; g2 < 64; ++g2) acc += em[g2] * tv[g2];
        eetab[tt * 3 + hh] = acc;
    }
}

__global__ __launch_bounds__(256) void k_prep(const float* __restrict__ W1,
        ushort* __restrict__ o1, const float* __restrict__ W2,
        ushort* __restrict__ o2, const float* __restrict__ W3,
        ushort* __restrict__ o3,
        const float* __restrict__ Eemb1, const float* __restrict__ We1,
        const float* __restrict__ ae1, float* __restrict__ ee1,
        const float* __restrict__ Eemb2, const float* __restrict__ We2,
        const float* __restrict__ ae2, float* __restrict__ ee2)
{
    int b = blockIdx.x;
    if (b < 48) {
        trans_tile(W1, o1, INF_, FEAT, b & 7, b >> 3);
    } else if (b < 84) {
        int i = b - 48;
        trans_tile(W2, o2, FEAT, FEAT, i % 6, i / 6);
    } else if (b < 120) {
        int i = b - 84;
        trans_tile(W3, o3, FEAT, FEAT, i % 6, i / 6);
    } else if (b == 120) {
        eetab_calc(Eemb1, We1, ae1, ee1);
    } else {
        eetab_calc(Eemb2, We2, ae2, ee2);
    }
}

// ---------------- GEMM1: 128-row tile, full-N(192), fused el/er --------------
#define LDA 40   // padded LDS row stride (ushort)
__global__ __launch_bounds__(256) void gemm_mfma1(const float* __restrict__ A,
        const ushort* __restrict__ BT, ushort* __restrict__ Cb,
        float4* __restrict__ el4, float4* __restrict__ er4,
        const float* __restrict__ al, const float* __restrict__ ar,
        int M, int K)
{
    __shared__ ushort As[128 * LDA];
    __shared__ ushort Bs[192 * LDA];
    const int t = threadIdx.x;
    const int lane = t & 63, w = t >> 6;
    const int bm = blockIdx.x * 128;
    const int fr = lane & 15;
    const int fq = lane >> 4;
    const int fg = fq * 8;
    const int arow = t >> 1;
    const int acol = (t & 1) * 8;
    const int brow = t >> 2;
    const int bcol = (t & 3) * 8;

    f32x4 acc[2][12];
    #pragma unroll
    for (int i = 0; i < 2; ++i)
        #pragma unroll
        for (int c = 0; c < 12; ++c)
            acc[i][c] = (f32x4){0.f, 0.f, 0.f, 0.f};

    const int ga = bm + arow;
    for (int k0 = 0; k0 < K; k0 += 32) {
        uint4 u0 = make_uint4(0,0,0,0), u1 = u0;
        if (ga < M) {
            const float* ap = A + (size_t)ga * K + k0 + acol;
            float4 f0 = ld4(ap), f1 = ld4(ap + 4);
            float4 f2v = ld4(ap + 16), f3 = ld4(ap + 20);
            u0 = make_uint4(pack2(f0.x,f0.y), pack2(f0.z,f0.w),
                            pack2(f1.x,f1.y), pack2(f1.z,f1.w));
            u1 = make_uint4(pack2(f2v.x,f2v.y), pack2(f2v.z,f2v.w),
                            pack2(f3.x,f3.y), pack2(f3.z,f3.w));
        }
        *reinterpret_cast<uint4*>(As + arow * LDA + acol) = u0;
        *reinterpret_cast<uint4*>(As + arow * LDA + acol + 16) = u1;
        #pragma unroll
        for (int j = 0; j < 3; ++j) {
            uint4 bv = *reinterpret_cast<const uint4*>(BT + (size_t)(j * 64 + brow) * K + k0 + bcol);
            *reinterpret_cast<uint4*>(Bs + (j * 64 + brow) * LDA + bcol) = bv;
        }
        __syncthreads();
        short8 afr0 = *reinterpret_cast<const short8*>(As + (w * 32 + fr) * LDA + fg);
        short8 afr1 = *reinterpret_cast<const short8*>(As + (w * 32 + 16 + fr) * LDA + fg);
        #pragma unroll
        for (int c = 0; c < 12; ++c) {
            short8 bfr = *reinterpret_cast<const short8*>(Bs + (c * 16 + fr) * LDA + fg);
            acc[0][c] = __builtin_amdgcn_mfma_f32_16x16x32_bf16(afr0, bfr, acc[0][c], 0, 0, 0);
            acc[1][c] = __builtin_amdgcn_mfma_f32_16x16x32_bf16(afr1, bfr, acc[1][c], 0, 0, 0);
        }
        __syncthreads();
    }
    #pragma unroll
    for (int i = 0; i < 2; ++i) {
        #pragma unroll
        for (int j = 0; j < 4; ++j) {
            int row = bm + w * 32 + i * 16 + fq * 4 + j;
            if (row < M) {
                #pragma unroll
                for (int c = 0; c < 12; ++c)
                    Cb[(size_t)row * FEAT + c * 16 + fr] = (ushort)f2b(acc[i][c][j]);
            }
        }
    }
    float alv[12], arv[12];
    #pragma unroll
    for (int c = 0; c < 12; ++c) {
        alv[c] = al[c * 16 + fr];
        arv[c] = ar[c * 16 + fr];
    }
    #pragma unroll
    for (int i = 0; i < 2; ++i) {
        #pragma unroll
        for (int j = 0; j < 4; ++j) {
            int row = bm + w * 32 + i * 16 + fq * 4 + j;
            float pl0 = 0.f, pl1 = 0.f, pl2 = 0.f;
            float pr0 = 0.f, pr1 = 0.f, pr2 = 0.f;
            #pragma unroll
            for (int c = 0; c < 4; ++c)  { pl0 += acc[i][c][j]*alv[c];  pr0 += acc[i][c][j]*arv[c]; }
            #pragma unroll
            for (int c = 4; c < 8; ++c)  { pl1 += acc[i][c][j]*alv[c];  pr1 += acc[i][c][j]*arv[c]; }
            #pragma unroll
            for (int c = 8; c < 12; ++c) { pl2 += acc[i][c][j]*alv[c];  pr2 += acc[i][c][j]*arv[c]; }
            #pragma unroll
            for (int o = 1; o < 16; o <<= 1) {
                pl0 += __shfl_xor(pl0, o); pl1 += __shfl_xor(pl1, o); pl2 += __shfl_xor(pl2, o);
                pr0 += __shfl_xor(pr0, o); pr1 += __shfl_xor(pr1, o); pr2 += __shfl_xor(pr2, o);
            }
            if (fr == 0 && row < M) {
                el4[row] = make_float4(pl0, pl1, pl2, 0.f);
                er4[row] = make_float4(pr0, pr1, pr2, 0.f);
            }
        }
    }
}

// ---------------- GEMM2: 64-row tile, dual-B, fused el/er --------------------
__global__ __launch_bounds__(256) void gemm_mfma2(const ushort* __restrict__ A,
        const ushort* __restrict__ BT, const ushort* __restrict__ BT2,
        ushort* __restrict__ Cb, ushort* __restrict__ resb,
        float4* __restrict__ el4, float4* __restrict__ er4,
        const float* __restrict__ al, const float* __restrict__ ar,
        int M, int K)
{
    __shared__ ushort As[64 * LDA];
    __shared__ ushort Bs[192 * LDA];
    __shared__ ushort Bs2[192 * LDA];
    const int t = threadIdx.x;
    const int lane = t & 63, w = t >> 6;
    const int bm = blockIdx.x * 64;
    const int fr = lane & 15;
    const int fq = lane >> 4;
    const int fg = fq * 8;
    const int arow = t >> 2;
    const int acol = (t & 3) * 8;
    const int brow = t >> 2;
    const int bcol = (t & 3) * 8;

    f32x4 acc[12], acc2[12];
    #pragma unroll
    for (int c = 0; c < 12; ++c) {
        acc[c] = (f32x4){0.f, 0.f, 0.f, 0.f};
        acc2[c] = (f32x4){0.f, 0.f, 0.f, 0.f};
    }

    const int ga = bm + arow;
    for (int k0 = 0; k0 < K; k0 += 32) {
        uint4 u0 = make_uint4(0,0,0,0);
        if (ga < M)
            u0 = *reinterpret_cast<const uint4*>(A + (size_t)ga * K + k0 + acol);
        *reinterpret_cast<uint4*>(As + arow * LDA + acol) = u0;
        #pragma unroll
        for (int j = 0; j < 3; ++j) {
            uint4 bv = *reinterpret_cast<const uint4*>(BT + (size_t)(j * 64 + brow) * K + k0 + bcol);
            *reinterpret_cast<uint4*>(Bs + (j * 64 + brow) * LDA + bcol) = bv;
            uint4 b2 = *reinterpret_cast<const uint4*>(BT2 + (size_t)(j * 64 + brow) * K + k0 + bcol);
            *reinterpret_cast<uint4*>(Bs2 + (j * 64 + brow) * LDA + bcol) = b2;
        }
        __syncthreads();
        short8 afr = *reinterpret_cast<const short8*>(As + (w * 16 + fr) * LDA + fg);
        #pragma unroll
        for (int c = 0; c < 12; ++c) {
            short8 bfr = *reinterpret_cast<const short8*>(Bs + (c * 16 + fr) * LDA + fg);
            acc[c] = __builtin_amdgcn_mfma_f32_16x16x32_bf16(afr, bfr, acc[c], 0, 0, 0);
            short8 b2 = *reinterpret_cast<const short8*>(Bs2 + (c * 16 + fr) * LDA + fg);
            acc2[c] = __builtin_amdgcn_mfma_f32_16x16x32_bf16(afr, b2, acc2[c], 0, 0, 0);
        }
        __syncthreads();
    }
    #pragma unroll
    for (int j = 0; j < 4; ++j) {
        int row = bm + w * 16 + fq * 4 + j;
        if (row < M) {
            #pragma unroll
            for (int c = 0; c < 12; ++c) {
                Cb[(size_t)row * FEAT + c * 16 + fr] = (ushort)f2b(acc[c][j]);
                resb[(size_t)row * FEAT + c * 16 + fr] = (ushort)f2b(acc2[c][j]);
            }
        }
    }
    float alv[12], arv[12];
    #pragma unroll
    for (int c = 0; c < 12; ++c) {
        alv[c] = al[c * 16 + fr];
        arv[c] = ar[c * 16 + fr];
    }
    #pragma unroll
    for (int j = 0; j < 4; ++j) {
        int row = bm + w * 16 + fq * 4 + j;
        float pl0 = 0.f, pl1 = 0.f, pl2 = 0.f;
        float pr0 = 0.f, pr1 = 0.f, pr2 = 0.f;
        #pragma unroll
        for (int c = 0; c < 4; ++c)  { pl0 += acc[c][j]*alv[c];  pr0 += acc[c][j]*arv[c]; }
        #pragma unroll
        for (int c = 4; c < 8; ++c)  { pl1 += acc[c][j]*alv[c];  pr1 += acc[c][j]*arv[c]; }
        #pragma unroll
        for (int c = 8; c < 12; ++c) { pl2 += acc[c][j]*alv[c];  pr2 += acc[c][j]*arv[c]; }
        #pragma unroll
        for (int o = 1; o < 16; o <<= 1) {
            pl0 += __shfl_xor(pl0, o); pl1 += __shfl_xor(pl1, o); pl2 += __shfl_xor(pl2, o);
            pr0 += __shfl_xor(pr0, o); pr1 += __shfl_xor(pr1, o); pr2 += __shfl_xor(pr2, o);
        }
        if (fr == 0 && row < M) {
            el4[row] = make_float4(pl0, pl1, pl2, 0.f);
            er4[row] = make_float4(pr0, pr1, pr2, 0.f);
        }
    }
}

// ---------------- CSR build: two-pass LDS-bucketed counting sort -------------
__global__ __launch_bounds__(256) void k_bucketA(const int* __restrict__ src,
        const int* __restrict__ dst, const int* __restrict__ et,
        int* __restrict__ bcnt, uint* __restrict__ bko)
{
    __shared__ uint recs[CHUNK];
    __shared__ ushort abk[CHUNK];
    __shared__ int hcnt[NBK], hoff[NBK], hcur[NBK], gb[NBK];
    const int t = threadIdx.x;
    const int e0 = blockIdx.x * CHUNK;
    if (t < NBK) hcnt[t] = 0;
    __syncthreads();
    uint rec[13];
    int  bk[13];
    #pragma unroll
    for (int k = 0; k < 13; ++k) {
        int i = t + k * 256;
        if (i < CHUNK) {
            int e = e0 + i;
            int s = src[e], d = dst[e], tt = et[e];
            rec[k] = (uint)s | ((uint)tt << 16) | ((uint)(d & 1023) << 19);
            bk[k] = d >> 10;
            atomicAdd(&hcnt[bk[k]], 1);
        } else {
            bk[k] = -1;
        }
    }
    __syncthreads();
    if (t < 64) {
        int v = (t < NBK) ? hcnt[t] : 0;
        int incl = v;
        #pragma unroll
        for (int o = 1; o < 64; o <<= 1) {
            int u = __shfl_up(incl, o);
            if (t >= o) incl += u;
        }
        if (t < NBK) { hoff[t] = incl - v; hcur[t] = incl - v; }
    }
    __syncthreads();
    #pragma unroll
    for (int k = 0; k < 13; ++k) {
        if (bk[k] >= 0) {
            int p = atomicAdd(&hcur[bk[k]], 1);
            recs[p] = rec[k];
            abk[p] = (ushort)bk[k];
        }
    }
    __syncthreads();
    if (t < NBK) gb[t] = atomicAdd(&bcnt[t], hcnt[t]);
    __syncthreads();
    for (int i = t; i < CHUNK; i += 256) {
        int b = abk[i];
        bko[(size_t)b * BKSTR + gb[b] + (i - hoff[b])] = recs[i];
    }
}

__global__ __launch_bounds__(64) void k_scanB(const int* __restrict__ bcnt,
        int* __restrict__ bexc, int* __restrict__ off)
{
    int t = threadIdx.x;
    int v = (t < NBK) ? bcnt[t] : 0;
    int incl = v;
    #pragma unroll
    for (int o = 1; o < 64; o <<= 1) {
        int u = __shfl_up(incl, o);
        if (t >= o) incl += u;
    }
    if (t < NBK) bexc[t] = incl - v;
    if (t == 63) off[NN] = incl;
}

__global__ __launch_bounds__(256) void k_bucketB(const int* __restrict__ bcnt,
        const int* __restrict__ bexc, const uint* __restrict__ bko,
        int* __restrict__ off, int* __restrict__ srcP)
{
    __shared__ int ldeg[1024], loff[1024];
    __shared__ int wsum[4];
    const int t = threadIdx.x, b = blockIdx.x;
    const int nd0 = b << 10;
    const int ncnt = min(1024, NN - nd0);
    const int ecnt = bcnt[b];
    const int base = bexc[b];
    const uint* rp = bko + (size_t)b * BKSTR;
    for (int i = t; i < 1024; i += 256) ldeg[i] = 0;
    __syncthreads();
    for (int i = t; i < ecnt; i += 256)
        atomicAdd(&ldeg[rp[i] >> 19], 1);
    __syncthreads();
    {
        int a0 = ldeg[4*t], a1 = ldeg[4*t+1], a2 = ldeg[4*t+2], a3 = ldeg[4*t+3];
        int s = a0 + a1 + a2 + a3;
        int incl = s;
        const int lane = t & 63;
        #pragma unroll
        for (int o = 1; o < 64; o <<= 1) {
            int u = __shfl_up(incl, o);
            if (lane >= o) incl += u;
        }
        int wid = t >> 6;
        if (lane == 63) wsum[wid] = incl;
        __syncthreads();
        int wb = 0;
        #pragma unroll
        for (int q = 0; q < 4; ++q) if (q < wid) wb += wsum[q];
        int tb = wb + incl - s;
        loff[4*t] = tb; loff[4*t+1] = tb + a0;
        loff[4*t+2] = tb + a0 + a1; loff[4*t+3] = tb + a0 + a1 + a2;
    }
    __syncthreads();
    for (int i = t; i < ncnt; i += 256) off[nd0 + i] = base + loff[i];
    for (int i = t; i < 1024; i += 256) ldeg[i] = loff[i];
    __syncthreads();
    for (int i = t; i < ecnt; i += 256) {
        uint rec = rp[i];
        int ld = rec >> 19;
        int p = base + atomicAdd(&ldeg[ld], 1);
        srcP[p] = (int)(((rec & 0xFFFFu) << 4) | (((rec >> 16) & 7u) << 28));
    }
}

// ---------------- fused edge-softmax + aggregation (16-lane group/node) ------
// 4 nodes per wave; lane gl owns elems {h*64 + gl*4 + 0..3} for h=0..2
#define EXTRACT(U, V01, V23) \
    f32x2 V01 = {blo((U).x), bhi((U).x)}; \
    f32x2 V23 = {blo((U).y), bhi((U).y)};

#define GBODY(WV) { \
    int bo = __float_as_int((WV).w); \
    uint2 x0 = *reinterpret_cast<const uint2*>(fb + bo); \
    uint2 x1 = *reinterpret_cast<const uint2*>(fb + bo + 128); \
    uint2 x2 = *reinterpret_cast<const uint2*>(fb + bo + 256); \
    EXTRACT(x0, v00, v01) \
    EXTRACT(x1, v10, v11) \
    EXTRACT(x2, v20, v21) \
    a00 += (WV).x * v00; a01 += (WV).x * v01; \
    a10 += (WV).y * v10; a11 += (WV).y * v11; \
    a20 += (WV).z * v20; a21 += (WV).z * v21; }

template<bool RES, bool FINAL>
__global__ __launch_bounds__(256) void k_attn_agg(const int* __restrict__ off,
        const int* __restrict__ srcP, const float4* __restrict__ el4,
        const float4* __restrict__ er4, const float* __restrict__ eetab,
        const ushort* __restrict__ featb, const ushort* __restrict__ resb,
        void* __restrict__ outv)
{
    __shared__ float shw[4][4][16][4];
    __shared__ float eet[24];
    const int w = threadIdx.x >> 6, lane = threadIdx.x & 63;
    const int g = lane >> 4, gl = lane & 15;
    if (threadIdx.x < 24) eet[threadIdx.x] = eetab[threadIdx.x];
    __syncthreads();
    const int n = blockIdx.x * 16 + w * 4 + g;     // 3125*16 = 50000 exact
    const int beg = off[n], end = off[n + 1];
    const int deg = end - beg;
    int degmax = max(deg, __shfl_xor(deg, 16));
    degmax = max(degmax, __shfl_xor(degmax, 32));
    const float4 erv = er4[n];
    const char* elc = (const char*)el4;
    const char* fb  = (const char*)featb + gl * 8;
    float* slot = &shw[w][g][gl][0];
    const float* sg = &shw[w][g][0][0];

    f32x2 a00 = {0.f,0.f}, a01 = {0.f,0.f};
    f32x2 a10 = {0.f,0.f}, a11 = {0.f,0.f};
    f32x2 a20 = {0.f,0.f}, a21 = {0.f,0.f};
    float dl0 = 0.f, dl1 = 0.f, dl2 = 0.f;

    for (int c0 = 0; c0 < degmax; c0 += 16) {
        float p0 = 0.f, p1 = 0.f, p2 = 0.f;
        int boff = 0;
        if (c0 + gl < deg) {
            int sp = srcP[beg + c0 + gl];
            int s16 = sp & SMASK;
            int tt = ((unsigned)sp) >> 28;
            float4 ev = *reinterpret_cast<const float4*>(elc + s16);
            float l0 = ev.x + erv.x + eet[tt*3+0];
            float l1 = ev.y + erv.y + eet[tt*3+1];
            float l2 = ev.z + erv.z + eet[tt*3+2];
            l0 = l0 > 0.f ? l0 : NEG_ * l0;
            l1 = l1 > 0.f ? l1 : NEG_ * l1;
            l2 = l2 > 0.f ? l2 : NEG_ * l2;
            p0 = __expf(l0); p1 = __expf(l1); p2 = __expf(l2);
            boff = s16 * 24;                   // s*384 bytes into featb
        }
        dl0 += p0; dl1 += p1; dl2 += p2;
        *reinterpret_cast<float4*>(slot) = make_float4(p0, p1, p2, __int_as_float(boff));
        int cnt = deg - c0;
        cnt = cnt < 0 ? 0 : (cnt > 16 ? 16 : cnt);
        int cmax = max(cnt, __shfl_xor(cnt, 16));
        cmax = max(cmax, __shfl_xor(cmax, 32));
        int j = 0;
        for (; j + 2 <= cmax; j += 2) {
            float4 wa = *reinterpret_cast<const float4*>(sg + (j+0)*4);
            float4 wb = *reinterpret_cast<const float4*>(sg + (j+1)*4);
            GBODY(wa)
            GBODY(wb)
        }
        if (j < cmax) {
            float4 wa = *reinterpret_cast<const float4*>(sg + j*4);
            GBODY(wa)
        }
    }
    #pragma unroll
    for (int o = 1; o < 16; o <<= 1) {
        dl0 += __shfl_xor(dl0, o);
        dl1 += __shfl_xor(dl1, o);
        dl2 += __shfl_xor(dl2, o);
    }
    const float i0 = 1.f / fmaxf(dl0, EPSF);
    const float i1 = 1.f / fmaxf(dl1, EPSF);
    const float i2 = 1.f / fmaxf(dl2, EPSF);
    float e0 = a00.x*i0, e1 = a00.y*i0, e2 = a01.x*i0, e3 = a01.y*i0;
    float q0 = a10.x*i1, q1 = a10.y*i1, q2 = a11.x*i1, q3 = a11.y*i1;
    float r0 = a20.x*i2, r1 = a20.y*i2, r2 = a21.x*i2, r3 = a21.y*i2;
    if (RES) {
        const char* rb = (const char*)resb + (size_t)n * 384 + gl * 8;
        uint2 u0 = *reinterpret_cast<const uint2*>(rb);
        uint2 u1 = *reinterpret_cast<const uint2*>(rb + 128);
        uint2 u2 = *reinterpret_cast<const uint2*>(rb + 256);
        e0 += blo(u0.x); e1 += bhi(u0.x); e2 += blo(u0.y); e3 += bhi(u0.y);
        q0 += blo(u1.x); q1 += bhi(u1.x); q2 += blo(u1.y); q3 += bhi(u1.y);
        r0 += blo(u2.x); r1 += bhi(u2.x); r2 += blo(u2.y); r3 += bhi(u2.y);
    }
#define ELUF(x) ((x) > 0.f ? (x) : __expf(x) - 1.f)
    e0 = ELUF(e0); e1 = ELUF(e1); e2 = ELUF(e2); e3 = ELUF(e3);
    q0 = ELUF(q0); q1 = ELUF(q1); q2 = ELUF(q2); q3 = ELUF(q3);
    r0 = ELUF(r0); r1 = ELUF(r1); r2 = ELUF(r2); r3 = ELUF(r3);
    if (!FINAL) {
        char* ob = (char*)outv + (size_t)n * 384 + gl * 8;
        *reinterpret_cast<uint2*>(ob)       = make_uint2(pack2(e0,e1), pack2(e2,e3));
        *reinterpret_cast<uint2*>(ob + 128) = make_uint2(pack2(q0,q1), pack2(q2,q3));
        *reinterpret_cast<uint2*>(ob + 256) = make_uint2(pack2(r0,r1), pack2(r2,r3));
    } else {
        float m0 = (e0 + q0 + r0) * (1.f / 3.f);
        float m1 = (e1 + q1 + r1) * (1.f / 3.f);
        float m2 = (e2 + q2 + r2) * (1.f / 3.f);
        float m3 = (e3 + q3 + r3) * (1.f / 3.f);
        float ss = m0*m0 + m1*m1 + m2*m2 + m3*m3;
        #pragma unroll
        for (int o = 1; o < 16; o <<= 1) ss += __shfl_xor(ss, o);
        float invn = 1.f / fmaxf(sqrtf(ss), EPSF);
        *reinterpret_cast<float4*>((float*)outv + (size_t)n * 64 + gl * 4) =
            make_float4(m0 * invn, m1 * invn, m2 * invn, m3 * invn);
    }
}

extern "C" void kernel_launch(void* const* d_in, const int* in_sizes, int n_in,
                              void* d_out, int out_size, void* d_ws, size_t ws_size,
                              hipStream_t stream)
{
    const float* x     = (const float*)d_in[0];
    const int*   src   = (const int*)d_in[1];
    const int*   dst   = (const int*)d_in[2];
    const int*   efeat = (const int*)d_in[3];
    const float* W1    = (const float*)d_in[4];
    const float* Eemb1 = (const float*)d_in[5];
    const float* We1   = (const float*)d_in[6];
    const float* al1   = (const float*)d_in[7];
    const float* ar1   = (const float*)d_in[8];
    const float* ae1   = (const float*)d_in[9];
    const float* W2    = (const float*)d_in[10];
    const float* Eemb2 = (const float*)d_in[11];
    const float* We2   = (const float*)d_in[12];
    const float* al2   = (const float*)d_in[13];
    const float* ar2   = (const float*)d_in[14];
    const float* ae2   = (const float*)d_in[15];
    const float* Wres2 = (const float*)d_in[16];

    char* w = (char*)d_ws;
    auto alloc = [&](size_t bytes) {
        char* p = w;
        w += (bytes + 255) & ~(size_t)255;
        return p;
    };
    ushort* featb = (ushort*)alloc((size_t)NN * FEAT * 2);
    ushort* h1b   = (ushort*)alloc((size_t)NN * FEAT * 2);
    ushort* resb  = (ushort*)alloc((size_t)NN * FEAT * 2);
    float4* el4   = (float4*)alloc((size_t)NN * 16);
    float4* er4   = (float4*)alloc((size_t)NN * 16);
    int*    off   = (int*)alloc((size_t)(NN + 1) * 4);
    int*    srcP  = (int*)alloc((size_t)EEN * 4);
    uint*   bko   = (uint*)alloc((size_t)NBK * BKSTR * 4);
    int*    bcnt  = (int*)alloc(64 * 4);
    int*    bexc  = (int*)alloc(64 * 4);
    ushort* w1bt  = (ushort*)alloc((size_t)FEAT * INF_ * 2);
    ushort* w2bt  = (ushort*)alloc((size_t)FEAT * FEAT * 2);
    ushort* wrbt  = (ushort*)alloc((size_t)FEAT * FEAT * 2);
    float*  ee1   = (float*)alloc(24 * 4);
    float*  ee2   = (float*)alloc(24 * 4);

    hipMemsetAsync(bcnt, 0, 64 * 4, stream);

    k_bucketA<<<EEN / CHUNK, 256, 0, stream>>>(src, dst, efeat, bcnt, bko);
    k_scanB<<<1, 64, 0, stream>>>(bcnt, bexc, off);
    k_bucketB<<<NBK, 256, 0, stream>>>(bcnt, bexc, bko, off, srcP);
    k_prep<<<122, 256, 0, stream>>>(W1, w1bt, W2, w2bt, Wres2, wrbt,
            Eemb1, We1, ae1, ee1, Eemb2, We2, ae2, ee2);

    const int ngb = NN / 16;   // 3125
    // ---- layer 1 ----
    gemm_mfma1<<<(NN + 127) / 128, 256, 0, stream>>>(x, w1bt, featb,
            el4, er4, al1, ar1, NN, INF_);
    k_attn_agg<false, false><<<ngb, 256, 0, stream>>>(off, srcP, el4, er4, ee1,
            featb, nullptr, h1b);
    // ---- layer 2 (W2 and Wres in one pass) ----
    gemm_mfma2<<<(NN + 63) / 64, 256, 0, stream>>>(h1b, w2bt, wrbt, featb,
            resb, el4, er4, al2, ar2, NN, FEAT);
    k_attn_agg<true, true><<<ngb, 256, 0, stream>>>(off, srcP, el4, er4, ee2,
            featb, resb, (float*)d_out);
}

// Round 13
// 210.588 us; speedup vs baseline: 1.2791x; 1.0174x over previous
//
#include <hip/hip_runtime.h>
#include <cstdint>
#include <cstddef>

#define NN   50000
#define EEN  800000
#define INF_ 256
#define HH   3
#define FEAT 192   // H*D
#define EFD  64
#define NEG_ 0.2f
#define EPSF 1e-12f
#define SMASK 0x0FFFFFF0   // s*16 field in srcP
#define NBK  49            // buckets = dst>>10
#define BKSTR 20480        // per-bucket capacity
#define CHUNK 3125         // edges per pass-A block

typedef __attribute__((ext_vector_type(8))) short short8;
typedef __attribute__((ext_vector_type(4))) float f32x4;
typedef __attribute__((ext_vector_type(2))) float f32x2;

static __device__ __forceinline__ float4 ld4(const float* p) {
    return *reinterpret_cast<const float4*>(p);
}
static __device__ __forceinline__ uint f2b(float f) {
    union { float f; uint32_t u; } v; v.f = f;
    uint32_t u = v.u;
    return (u + 0x7FFFu + ((u >> 16) & 1u)) >> 16;
}
static __device__ __forceinline__ uint pack2(float a, float b) {
    return f2b(a) | (f2b(b) << 16);
}
static __device__ __forceinline__ float blo(uint u) {
    return __uint_as_float(u << 16);
}
static __device__ __forceinline__ float bhi(uint u) {
    return __uint_as_float(u & 0xFFFF0000u);
}

// ---------------- prep: weight transposes (blocks 0..119) + eetab (120,121) --
static __device__ __forceinline__ void trans_tile(const float* __restrict__ W,
        ushort* __restrict__ BT, int K, int N, int kt, int nt)
{
    __shared__ float tile[32][33];
    const int tx = threadIdx.x & 31, ty = threadIdx.x >> 5;  // 32 x 8
    #pragma unroll
    for (int r = 0; r < 4; ++r) {
        int row = kt * 32 + ty + r * 8;
        int col = nt * 32 + tx;
        tile[ty + r * 8][tx] = W[(size_t)row * N + col];
    }
    __syncthreads();
    #pragma unroll
    for (int r = 0; r < 4; ++r) {
        int n = nt * 32 + ty + r * 8;
        int k = kt * 32 + tx;
        BT[(size_t)n * K + k] = (ushort)f2b(tile[tx][ty + r * 8]);
    }
}

static __device__ __forceinline__ void eetab_calc(const float* __restrict__ Eemb,
        const float* __restrict__ We, const float* __restrict__ ae,
        float* __restrict__ eetab)
{
    __shared__ float t1[3 * 64];
    const int t = threadIdx.x;
    if (t < 192) {
        const int g = t & 63, h = t >> 6;
        const float* wrow = We + g * FEAT + h * EFD;
        const float* av   = ae + h * EFD;
        float s = 0.f;
        #pragma unroll 8
        for (int f = 0; f < EFD; ++f) s += wrow[f] * av[f];
        t1[h * 64 + g] = s;
    }
    __syncthreads();
    if (t < 24) {
        int tt = t / 3, hh = t - tt * 3;
        float acc = 0.f;
        const float* em = Eemb + tt * EFD;
        const float* tv = t1 + hh * 64;
        #pragma unroll 8
        for (int g2 = 0; g2 < 64; ++g2) acc += em[g2] * tv[g2];
        eetab[tt * 3 + hh] = acc;
    }
}

__global__ __launch_bounds__(256) void k_prep(const float* __restrict__ W1,
        ushort* __restrict__ o1, const float* __restrict__ W2,
        ushort* __restrict__ o2, const float* __restrict__ W3,
        ushort* __restrict__ o3,
        const float* __restrict__ Eemb1, const float* __restrict__ We1,
        const float* __restrict__ ae1, float* __restrict__ ee1,
        const float* __restrict__ Eemb2, const float* __restrict__ We2,
        const float* __restrict__ ae2, float* __restrict__ ee2)
{
    int b = blockIdx.x;
    if (b < 48) {
        trans_tile(W1, o1, INF_, FEAT, b & 7, b >> 3);
    } else if (b < 84) {
        int i = b - 48;
        trans_tile(W2, o2, FEAT, FEAT, i % 6, i / 6);
    } else if (b < 120) {
        int i = b - 84;
        trans_tile(W3, o3, FEAT, FEAT, i % 6, i / 6);
    } else if (b == 120) {
        eetab_calc(Eemb1, We1, ae1, ee1);
    } else {
        eetab_calc(Eemb2, We2, ae2, ee2);
    }
}

// ---------------- GEMM1: 128-row tile, full-N(192), fused el/er --------------
#define LDA 40   // padded LDS row stride (ushort)
__global__ __launch_bounds__(256) void gemm_mfma1(const float* __restrict__ A,
        const ushort* __restrict__ BT, ushort* __restrict__ Cb,
        float4* __restrict__ el4, float4* __restrict__ er4,
        const float* __restrict__ al, const float* __restrict__ ar,
        int M, int K)
{
    __shared__ ushort As[128 * LDA];
    __shared__ ushort Bs[192 * LDA];
    const int t = threadIdx.x;
    const int lane = t & 63, w = t >> 6;
    const int bm = blockIdx.x * 128;
    const int fr = lane & 15;
    const int fq = lane >> 4;
    const int fg = fq * 8;
    const int arow = t >> 1;
    const int acol = (t & 1) * 8;
    const int brow = t >> 2;
    const int bcol = (t & 3) * 8;

    f32x4 acc[2][12];
    #pragma unroll
    for (int i = 0; i < 2; ++i)
        #pragma unroll
        for (int c = 0; c < 12; ++c)
            acc[i][c] = (f32x4){0.f, 0.f, 0.f, 0.f};

    const int ga = bm + arow;
    for (int k0 = 0; k0 < K; k0 += 32) {
        uint4 u0 = make_uint4(0,0,0,0), u1 = u0;
        if (ga < M) {
            const float* ap = A + (size_t)ga * K + k0 + acol;
            float4 f0 = ld4(ap), f1 = ld4(ap + 4);
            float4 f2v = ld4(ap + 16), f3 = ld4(ap + 20);
            u0 = make_uint4(pack2(f0.x,f0.y), pack2(f0.z,f0.w),
                            pack2(f1.x,f1.y), pack2(f1.z,f1.w));
            u1 = make_uint4(pack2(f2v.x,f2v.y), pack2(f2v.z,f2v.w),
                            pack2(f3.x,f3.y), pack2(f3.z,f3.w));
        }
        *reinterpret_cast<uint4*>(As + arow * LDA + acol) = u0;
        *reinterpret_cast<uint4*>(As + arow * LDA + acol + 16) = u1;
        #pragma unroll
        for (int j = 0; j < 3; ++j) {
            uint4 bv = *reinterpret_cast<const uint4*>(BT + (size_t)(j * 64 + brow) * K + k0 + bcol);
            *reinterpret_cast<uint4*>(Bs + (j * 64 + brow) * LDA + bcol) = bv;
        }
        __syncthreads();
        short8 afr0 = *reinterpret_cast<const short8*>(As + (w * 32 + fr) * LDA + fg);
        short8 afr1 = *reinterpret_cast<const short8*>(As + (w * 32 + 16 + fr) * LDA + fg);
        #pragma unroll
        for (int c = 0; c < 12; ++c) {
            short8 bfr = *reinterpret_cast<const short8*>(Bs + (c * 16 + fr) * LDA + fg);
            acc[0][c] = __builtin_amdgcn_mfma_f32_16x16x32_bf16(afr0, bfr, acc[0][c], 0, 0, 0);
            acc[1][c] = __builtin_amdgcn_mfma_f32_16x16x32_bf16(afr1, bfr, acc[1][c], 0, 0, 0);
        }
        __syncthreads();
    }
    #pragma unroll
    for (int i = 0; i < 2; ++i) {
        #pragma unroll
        for (int j = 0; j < 4; ++j) {
            int row = bm + w * 32 + i * 16 + fq * 4 + j;
            if (row < M) {
                #pragma unroll
                for (int c = 0; c < 12; ++c)
                    Cb[(size_t)row * FEAT + c * 16 + fr] = (ushort)f2b(acc[i][c][j]);
            }
        }
    }
    float alv[12], arv[12];
    #pragma unroll
    for (int c = 0; c < 12; ++c) {
        alv[c] = al[c * 16 + fr];
        arv[c] = ar[c * 16 + fr];
    }
    #pragma unroll
    for (int i = 0; i < 2; ++i) {
        #pragma unroll
        for (int j = 0; j < 4; ++j) {
            int row = bm + w * 32 + i * 16 + fq * 4 + j;
            float pl0 = 0.f, pl1 = 0.f, pl2 = 0.f;
            float pr0 = 0.f, pr1 = 0.f, pr2 = 0.f;
            #pragma unroll
            for (int c = 0; c < 4; ++c)  { pl0 += acc[i][c][j]*alv[c];  pr0 += acc[i][c][j]*arv[c]; }
            #pragma unroll
            for (int c = 4; c < 8; ++c)  { pl1 += acc[i][c][j]*alv[c];  pr1 += acc[i][c][j]*arv[c]; }
            #pragma unroll
            for (int c = 8; c < 12; ++c) { pl2 += acc[i][c][j]*alv[c];  pr2 += acc[i][c][j]*arv[c]; }
            #pragma unroll
            for (int o = 1; o < 16; o <<= 1) {
                pl0 += __shfl_xor(pl0, o); pl1 += __shfl_xor(pl1, o); pl2 += __shfl_xor(pl2, o);
                pr0 += __shfl_xor(pr0, o); pr1 += __shfl_xor(pr1, o); pr2 += __shfl_xor(pr2, o);
            }
            if (fr == 0 && row < M) {
                el4[row] = make_float4(pl0, pl1, pl2, 0.f);
                er4[row] = make_float4(pr0, pr1, pr2, 0.f);
            }
        }
    }
}

// ---------------- GEMM2: 64-row tile, dual-B, fused el/er --------------------
__global__ __launch_bounds__(256) void gemm_mfma2(const ushort* __restrict__ A,
        const ushort* __restrict__ BT, const ushort* __restrict__ BT2,
        ushort* __restrict__ Cb, ushort* __restrict__ resb,
        float4* __restrict__ el4, float4* __restrict__ er4,
        const float* __restrict__ al, const float* __restrict__ ar,
        int M, int K)
{
    __shared__ ushort As[64 * LDA];
    __shared__ ushort Bs[192 * LDA];
    __shared__ ushort Bs2[192 * LDA];
    const int t = threadIdx.x;
    const int lane = t & 63, w = t >> 6;
    const int bm = blockIdx.x * 64;
    const int fr = lane & 15;
    const int fq = lane >> 4;
    const int fg = fq * 8;
    const int arow = t >> 2;
    const int acol = (t & 3) * 8;
    const int brow = t >> 2;
    const int bcol = (t & 3) * 8;

    f32x4 acc[12], acc2[12];
    #pragma unroll
    for (int c = 0; c < 12; ++c) {
        acc[c] = (f32x4){0.f, 0.f, 0.f, 0.f};
        acc2[c] = (f32x4){0.f, 0.f, 0.f, 0.f};
    }

    const int ga = bm + arow;
    for (int k0 = 0; k0 < K; k0 += 32) {
        uint4 u0 = make_uint4(0,0,0,0);
        if (ga < M)
            u0 = *reinterpret_cast<const uint4*>(A + (size_t)ga * K + k0 + acol);
        *reinterpret_cast<uint4*>(As + arow * LDA + acol) = u0;
        #pragma unroll
        for (int j = 0; j < 3; ++j) {
            uint4 bv = *reinterpret_cast<const uint4*>(BT + (size_t)(j * 64 + brow) * K + k0 + bcol);
            *reinterpret_cast<uint4*>(Bs + (j * 64 + brow) * LDA + bcol) = bv;
            uint4 b2 = *reinterpret_cast<const uint4*>(BT2 + (size_t)(j * 64 + brow) * K + k0 + bcol);
            *reinterpret_cast<uint4*>(Bs2 + (j * 64 + brow) * LDA + bcol) = b2;
        }
        __syncthreads();
        short8 afr = *reinterpret_cast<const short8*>(As + (w * 16 + fr) * LDA + fg);
        #pragma unroll
        for (int c = 0; c < 12; ++c) {
            short8 bfr = *reinterpret_cast<const short8*>(Bs + (c * 16 + fr) * LDA + fg);
            acc[c] = __builtin_amdgcn_mfma_f32_16x16x32_bf16(afr, bfr, acc[c], 0, 0, 0);
            short8 b2 = *reinterpret_cast<const short8*>(Bs2 + (c * 16 + fr) * LDA + fg);
            acc2[c] = __builtin_amdgcn_mfma_f32_16x16x32_bf16(afr, b2, acc2[c], 0, 0, 0);
        }
        __syncthreads();
    }
    #pragma unroll
    for (int j = 0; j < 4; ++j) {
        int row = bm + w * 16 + fq * 4 + j;
        if (row < M) {
            #pragma unroll
            for (int c = 0; c < 12; ++c) {
                Cb[(size_t)row * FEAT + c * 16 + fr] = (ushort)f2b(acc[c][j]);
                resb[(size_t)row * FEAT + c * 16 + fr] = (ushort)f2b(acc2[c][j]);
            }
        }
    }
    float alv[12], arv[12];
    #pragma unroll
    for (int c = 0; c < 12; ++c) {
        alv[c] = al[c * 16 + fr];
        arv[c] = ar[c * 16 + fr];
    }
    #pragma unroll
    for (int j = 0; j < 4; ++j) {
        int row = bm + w * 16 + fq * 4 + j;
        float pl0 = 0.f, pl1 = 0.f, pl2 = 0.f;
        float pr0 = 0.f, pr1 = 0.f, pr2 = 0.f;
        #pragma unroll
        for (int c = 0; c < 4; ++c)  { pl0 += acc[c][j]*alv[c];  pr0 += acc[c][j]*arv[c]; }
        #pragma unroll
        for (int c = 4; c < 8; ++c)  { pl1 += acc[c][j]*alv[c];  pr1 += acc[c][j]*arv[c]; }
        #pragma unroll
        for (int c = 8; c < 12; ++c) { pl2 += acc[c][j]*alv[c];  pr2 += acc[c][j]*arv[c]; }
        #pragma unroll
        for (int o = 1; o < 16; o <<= 1) {
            pl0 += __shfl_xor(pl0, o); pl1 += __shfl_xor(pl1, o); pl2 += __shfl_xor(pl2, o);
            pr0 += __shfl_xor(pr0, o); pr1 += __shfl_xor(pr1, o); pr2 += __shfl_xor(pr2, o);
        }
        if (fr == 0 && row < M) {
            el4[row] = make_float4(pl0, pl1, pl2, 0.f);
            er4[row] = make_float4(pr0, pr1, pr2, 0.f);
        }
    }
}

// ---------------- CSR build: two-pass LDS-bucketed counting sort -------------
__global__ __launch_bounds__(256) void k_bucketA(const int* __restrict__ src,
        const int* __restrict__ dst, const int* __restrict__ et,
        int* __restrict__ bcnt, uint* __restrict__ bko)
{
    __shared__ uint recs[CHUNK];
    __shared__ ushort abk[CHUNK];
    __shared__ int hcnt[NBK], hoff[NBK], hcur[NBK], gb[NBK];
    const int t = threadIdx.x;
    const int e0 = blockIdx.x * CHUNK;
    if (t < NBK) hcnt[t] = 0;
    __syncthreads();
    uint rec[13];
    int  bk[13];
    #pragma unroll
    for (int k = 0; k < 13; ++k) {
        int i = t + k * 256;
        if (i < CHUNK) {
            int e = e0 + i;
            int s = src[e], d = dst[e], tt = et[e];
            rec[k] = (uint)s | ((uint)tt << 16) | ((uint)(d & 1023) << 19);
            bk[k] = d >> 10;
            atomicAdd(&hcnt[bk[k]], 1);
        } else {
            bk[k] = -1;
        }
    }
    __syncthreads();
    if (t < 64) {
        int v = (t < NBK) ? hcnt[t] : 0;
        int incl = v;
        #pragma unroll
        for (int o = 1; o < 64; o <<= 1) {
            int u = __shfl_up(incl, o);
            if (t >= o) incl += u;
        }
        if (t < NBK) { hoff[t] = incl - v; hcur[t] = incl - v; }
    }
    __syncthreads();
    #pragma unroll
    for (int k = 0; k < 13; ++k) {
        if (bk[k] >= 0) {
            int p = atomicAdd(&hcur[bk[k]], 1);
            recs[p] = rec[k];
            abk[p] = (ushort)bk[k];
        }
    }
    __syncthreads();
    if (t < NBK) gb[t] = atomicAdd(&bcnt[t], hcnt[t]);
    __syncthreads();
    for (int i = t; i < CHUNK; i += 256) {
        int b = abk[i];
        bko[(size_t)b * BKSTR + gb[b] + (i - hoff[b])] = recs[i];
    }
}

__global__ __launch_bounds__(64) void k_scanB(const int* __restrict__ bcnt,
        int* __restrict__ bexc, int* __restrict__ off)
{
    int t = threadIdx.x;
    int v = (t < NBK) ? bcnt[t] : 0;
    int incl = v;
    #pragma unroll
    for (int o = 1; o < 64; o <<= 1) {
        int u = __shfl_up(incl, o);
        if (t >= o) incl += u;
    }
    if (t < NBK) bexc[t] = incl - v;
    if (t == 63) off[NN] = incl;
}

__global__ __launch_bounds__(256) void k_bucketB(const int* __restrict__ bcnt,
        const int* __restrict__ bexc, const uint* __restrict__ bko,
        int* __restrict__ off, int* __restrict__ srcP)
{
    __shared__ int ldeg[1024], loff[1024];
    __shared__ int wsum[4];
    const int t = threadIdx.x, b = blockIdx.x;
    const int nd0 = b << 10;
    const int ncnt = min(1024, NN - nd0);
    const int ecnt = bcnt[b];
    const int base = bexc[b];
    const uint* rp = bko + (size_t)b * BKSTR;
    for (int i = t; i < 1024; i += 256) ldeg[i] = 0;
    __syncthreads();
    for (int i = t; i < ecnt; i += 256)
        atomicAdd(&ldeg[rp[i] >> 19], 1);
    __syncthreads();
    {
        int a0 = ldeg[4*t], a1 = ldeg[4*t+1], a2 = ldeg[4*t+2], a3 = ldeg[4*t+3];
        int s = a0 + a1 + a2 + a3;
        int incl = s;
        const int lane = t & 63;
        #pragma unroll
        for (int o = 1; o < 64; o <<= 1) {
            int u = __shfl_up(incl, o);
            if (lane >= o) incl += u;
        }
        int wid = t >> 6;
        if (lane == 63) wsum[wid] = incl;
        __syncthreads();
        int wb = 0;
        #pragma unroll
        for (int q = 0; q < 4; ++q) if (q < wid) wb += wsum[q];
        int tb = wb + incl - s;
        loff[4*t] = tb; loff[4*t+1] = tb + a0;
        loff[4*t+2] = tb + a0 + a1; loff[4*t+3] = tb + a0 + a1 + a2;
    }
    __syncthreads();
    for (int i = t; i < ncnt; i += 256) off[nd0 + i] = base + loff[i];
    for (int i = t; i < 1024; i += 256) ldeg[i] = loff[i];
    __syncthreads();
    for (int i = t; i < ecnt; i += 256) {
        uint rec = rp[i];
        int ld = rec >> 19;
        int p = base + atomicAdd(&ldeg[ld], 1);
        srcP[p] = (int)(((rec & 0xFFFFu) << 4) | (((rec >> 16) & 7u) << 28));
    }
}

// ---------------- fused edge-softmax + aggregation (16-lane group/node) ------
// 4 nodes per wave; lane gl owns elems {h*64 + gl*4 + 0..3} for h=0..2
// LDS group stride padded to 17 rows (272B) -> conflict-free weight broadcast
#define EXTRACT(U, V01, V23) \
    f32x2 V01 = {blo((U).x), bhi((U).x)}; \
    f32x2 V23 = {blo((U).y), bhi((U).y)};

#define GBODY(WV) { \
    int bo = __float_as_int((WV).w); \
    uint2 x0 = *reinterpret_cast<const uint2*>(fb + bo); \
    uint2 x1 = *reinterpret_cast<const uint2*>(fb + bo + 128); \
    uint2 x2 = *reinterpret_cast<const uint2*>(fb + bo + 256); \
    EXTRACT(x0, v00, v01) \
    EXTRACT(x1, v10, v11) \
    EXTRACT(x2, v20, v21) \
    a00 += (WV).x * v00; a01 += (WV).x * v01; \
    a10 += (WV).y * v10; a11 += (WV).y * v11; \
    a20 += (WV).z * v20; a21 += (WV).z * v21; }

template<bool RES, bool FINAL>
__global__ __launch_bounds__(256) void k_attn_agg(const int* __restrict__ off,
        const int* __restrict__ srcP, const float4* __restrict__ el4,
        const float4* __restrict__ er4, const float* __restrict__ eetab,
        const ushort* __restrict__ featb, const ushort* __restrict__ resb,
        void* __restrict__ outv)
{
    __shared__ float shw[4][4][17][4];
    __shared__ float eet[24];
    const int w = threadIdx.x >> 6, lane = threadIdx.x & 63;
    const int g = lane >> 4, gl = lane & 15;
    if (threadIdx.x < 24) eet[threadIdx.x] = eetab[threadIdx.x];
    __syncthreads();
    // bijective XCD swizzle: nwg=3125 = 5*391 + 3*390
    const int bid = blockIdx.x;
    const int xcd = bid & 7, bix = bid >> 3;
    const int wg = (xcd < 5 ? xcd * 391 : 5 * 391 + (xcd - 5) * 390) + bix;
    const int n = wg * 16 + w * 4 + g;
    const int beg = off[n], end = off[n + 1];
    const int deg = end - beg;
    int degmax = max(deg, __shfl_xor(deg, 16));
    degmax = max(degmax, __shfl_xor(degmax, 32));
    const float4 erv = er4[n];
    const char* elc = (const char*)el4;
    const char* fb  = (const char*)featb + gl * 8;
    float* slot = &shw[w][g][gl][0];
    const float* sg = &shw[w][g][0][0];

    f32x2 a00 = {0.f,0.f}, a01 = {0.f,0.f};
    f32x2 a10 = {0.f,0.f}, a11 = {0.f,0.f};
    f32x2 a20 = {0.f,0.f}, a21 = {0.f,0.f};
    float dl0 = 0.f, dl1 = 0.f, dl2 = 0.f;

    // prefetch chunk 0
    bool vld = gl < deg;
    int sp = vld ? srcP[beg + gl] : 0;
    float4 ev = vld ? *reinterpret_cast<const float4*>(elc + (sp & SMASK))
                    : make_float4(0.f, 0.f, 0.f, 0.f);

    for (int c0 = 0; c0 < degmax; c0 += 16) {
        float p0 = 0.f, p1 = 0.f, p2 = 0.f;
        int boff = 0;
        if (vld) {
            int s16 = sp & SMASK;
            int tt = ((unsigned)sp) >> 28;
            float l0 = ev.x + erv.x + eet[tt*3+0];
            float l1 = ev.y + erv.y + eet[tt*3+1];
            float l2 = ev.z + erv.z + eet[tt*3+2];
            l0 = l0 > 0.f ? l0 : NEG_ * l0;
            l1 = l1 > 0.f ? l1 : NEG_ * l1;
            l2 = l2 > 0.f ? l2 : NEG_ * l2;
            p0 = __expf(l0); p1 = __expf(l1); p2 = __expf(l2);
            boff = s16 * 24;                   // s*384 bytes into featb
        }
        dl0 += p0; dl1 += p1; dl2 += p2;
        *reinterpret_cast<float4*>(slot) = make_float4(p0, p1, p2, __int_as_float(boff));
        int cnt = deg - c0;
        cnt = cnt < 0 ? 0 : (cnt > 16 ? 16 : cnt);
        int cmax = max(cnt, __shfl_xor(cnt, 16));
        cmax = max(cmax, __shfl_xor(cmax, 32));
        // prefetch next chunk (hides srcP->el4 chain under gather)
        const int nc = c0 + 16;
        if (nc < degmax) {
            vld = (nc + gl) < deg;
            sp = vld ? srcP[beg + nc + gl] : 0;
            ev = vld ? *reinterpret_cast<const float4*>(elc + (sp & SMASK))
                     : make_float4(0.f, 0.f, 0.f, 0.f);
        }
        int j = 0;
        for (; j + 4 <= cmax; j += 4) {
            float4 wa = *reinterpret_cast<const float4*>(sg + (j+0)*4);
            float4 wb = *reinterpret_cast<const float4*>(sg + (j+1)*4);
            float4 wc = *reinterpret_cast<const float4*>(sg + (j+2)*4);
            float4 wd = *reinterpret_cast<const float4*>(sg + (j+3)*4);
            GBODY(wa)
            GBODY(wb)
            GBODY(wc)
            GBODY(wd)
        }
        for (; j < cmax; ++j) {
            float4 wa = *reinterpret_cast<const float4*>(sg + j*4);
            GBODY(wa)
        }
    }
    #pragma unroll
    for (int o = 1; o < 16; o <<= 1) {
        dl0 += __shfl_xor(dl0, o);
        dl1 += __shfl_xor(dl1, o);
        dl2 += __shfl_xor(dl2, o);
    }
    const float i0 = 1.f / fmaxf(dl0, EPSF);
    const float i1 = 1.f / fmaxf(dl1, EPSF);
    const float i2 = 1.f / fmaxf(dl2, EPSF);
    float e0 = a00.x*i0, e1 = a00.y*i0, e2 = a01.x*i0, e3 = a01.y*i0;
    float q0 = a10.x*i1, q1 = a10.y*i1, q2 = a11.x*i1, q3 = a11.y*i1;
    float r0 = a20.x*i2, r1 = a20.y*i2, r2 = a21.x*i2, r3 = a21.y*i2;
    if (RES) {
        const char* rb = (const char*)resb + (size_t)n * 384 + gl * 8;
        uint2 u0 = *reinterpret_cast<const uint2*>(rb);
        uint2 u1 = *reinterpret_cast<const uint2*>(rb + 128);
        uint2 u2 = *reinterpret_cast<const uint2*>(rb + 256);
        e0 += blo(u0.x); e1 += bhi(u0.x); e2 += blo(u0.y); e3 += bhi(u0.y);
        q0 += blo(u1.x); q1 += bhi(u1.x); q2 += blo(u1.y); q3 += bhi(u1.y);
        r0 += blo(u2.x); r1 += bhi(u2.x); r2 += blo(u2.y); r3 += bhi(u2.y);
    }
#define ELUF(x) ((x) > 0.f ? (x) : __expf(x) - 1.f)
    e0 = ELUF(e0); e1 = ELUF(e1); e2 = ELUF(e2); e3 = ELUF(e3);
    q0 = ELUF(q0); q1 = ELUF(q1); q2 = ELUF(q2); q3 = ELUF(q3);
    r0 = ELUF(r0); r1 = ELUF(r1); r2 = ELUF(r2); r3 = ELUF(r3);
    if (!FINAL) {
        char* ob = (char*)outv + (size_t)n * 384 + gl * 8;
        *reinterpret_cast<uint2*>(ob)       = make_uint2(pack2(e0,e1), pack2(e2,e3));
        *reinterpret_cast<uint2*>(ob + 128) = make_uint2(pack2(q0,q1), pack2(q2,q3));
        *reinterpret_cast<uint2*>(ob + 256) = make_uint2(pack2(r0,r1), pack2(r2,r3));
    } else {
        float m0 = (e0 + q0 + r0) * (1.f / 3.f);
        float m1 = (e1 + q1 + r1) * (1.f / 3.f);
        float m2 = (e2 + q2 + r2) * (1.f / 3.f);
        float m3 = (e3 + q3 + r3) * (1.f / 3.f);
        float ss = m0*m0 + m1*m1 + m2*m2 + m3*m3;
        #pragma unroll
        for (int o = 1; o < 16; o <<= 1) ss += __shfl_xor(ss, o);
        float invn = 1.f / fmaxf(sqrtf(ss), EPSF);
        *reinterpret_cast<float4*>((float*)outv + (size_t)n * 64 + gl * 4) =
            make_float4(m0 * invn, m1 * invn, m2 * invn, m3 * invn);
    }
}

extern "C" void kernel_launch(void* const* d_in, const int* in_sizes, int n_in,
                              void* d_out, int out_size, void* d_ws, size_t ws_size,
                              hipStream_t stream)
{
    const float* x     = (const float*)d_in[0];
    const int*   src   = (const int*)d_in[1];
    const int*   dst   = (const int*)d_in[2];
    const int*   efeat = (const int*)d_in[3];
    const float* W1    = (const float*)d_in[4];
    const float* Eemb1 = (const float*)d_in[5];
    const float* We1   = (const float*)d_in[6];
    const float* al1   = (const float*)d_in[7];
    const float* ar1   = (const float*)d_in[8];
    const float* ae1   = (const float*)d_in[9];
    const float* W2    = (const float*)d_in[10];
    const float* Eemb2 = (const float*)d_in[11];
    const float* We2   = (const float*)d_in[12];
    const float* al2   = (const float*)d_in[13];
    const float* ar2   = (const float*)d_in[14];
    const float* ae2   = (const float*)d_in[15];
    const float* Wres2 = (const float*)d_in[16];

    char* w = (char*)d_ws;
    auto alloc = [&](size_t bytes) {
        char* p = w;
        w += (bytes + 255) & ~(size_t)255;
        return p;
    };
    ushort* featb = (ushort*)alloc((size_t)NN * FEAT * 2);
    ushort* h1b   = (ushort*)alloc((size_t)NN * FEAT * 2);
    ushort* resb  = (ushort*)alloc((size_t)NN * FEAT * 2);
    float4* el4   = (float4*)alloc((size_t)NN * 16);
    float4* er4   = (float4*)alloc((size_t)NN * 16);
    int*    off   = (int*)alloc((size_t)(NN + 1) * 4);
    int*    srcP  = (int*)alloc((size_t)EEN * 4);
    uint*   bko   = (uint*)alloc((size_t)NBK * BKSTR * 4);
    int*    bcnt  = (int*)alloc(64 * 4);
    int*    bexc  = (int*)alloc(64 * 4);
    ushort* w1bt  = (ushort*)alloc((size_t)FEAT * INF_ * 2);
    ushort* w2bt  = (ushort*)alloc((size_t)FEAT * FEAT * 2);
    ushort* wrbt  = (ushort*)alloc((size_t)FEAT * FEAT * 2);
    float*  ee1   = (float*)alloc(24 * 4);
    float*  ee2   = (float*)alloc(24 * 4);

    hipMemsetAsync(bcnt, 0, 64 * 4, stream);

    k_bucketA<<<EEN / CHUNK, 256, 0, stream>>>(src, dst, efeat, bcnt, bko);
    k_scanB<<<1, 64, 0, stream>>>(bcnt, bexc, off);
    k_bucketB<<<NBK, 256, 0, stream>>>(bcnt, bexc, bko, off, srcP);
    k_prep<<<122, 256, 0, stream>>>(W1, w1bt, W2, w2bt, Wres2, wrbt,
            Eemb1, We1, ae1, ee1, Eemb2, We2, ae2, ee2);

    const int ngb = NN / 16;   // 3125
    // ---- layer 1 ----
    gemm_mfma1<<<(NN + 127) / 128, 256, 0, stream>>>(x, w1bt, featb,
            el4, er4, al1, ar1, NN, INF_);
    k_attn_agg<false, false><<<ngb, 256, 0, stream>>>(off, srcP, el4, er4, ee1,
            featb, nullptr, h1b);
    // ---- layer 2 (W2 and Wres in one pass) ----
    gemm_mfma2<<<(NN + 63) / 64, 256, 0, stream>>>(h1b, w2bt, wrbt, featb,
            resb, el4, er4, al2, ar2, NN, FEAT);
    k_attn_agg<true, true><<<ngb, 256, 0, stream>>>(off, srcP, el4, er4, ee2,
            featb, resb, (float*)d_out);
}